// Round 9
// baseline (316.895 us; speedup 1.0000x reference)
//
#include <hip/hip_runtime.h>
#include <cstdint>
#include <cstddef>

#define NN 8000
#define EE 64000
#define HH 10

typedef __attribute__((ext_vector_type(8))) short bf16x8;
typedef __attribute__((ext_vector_type(4))) float f32x4;
typedef __attribute__((ext_vector_type(4))) unsigned int u32x4;

__device__ __forceinline__ int rfl(int v) { return __builtin_amdgcn_readfirstlane(v); }

// ---- pack 8 consecutive f32 into one bf16x8 fragment (truncation)
__device__ __forceinline__ bf16x8 pack8(f32x4 a, f32x4 b) {
  u32x4 u;
  u[0] = (__float_as_uint(a[1]) & 0xFFFF0000u) | (__float_as_uint(a[0]) >> 16);
  u[1] = (__float_as_uint(a[3]) & 0xFFFF0000u) | (__float_as_uint(a[2]) >> 16);
  u[2] = (__float_as_uint(b[1]) & 0xFFFF0000u) | (__float_as_uint(b[0]) >> 16);
  u[3] = (__float_as_uint(b[3]) & 0xFFFF0000u) | (__float_as_uint(b[2]) >> 16);
  return __builtin_bit_cast(bf16x8, u);
}

__device__ __forceinline__ f32x4 relu4(f32x4 a, f32x4 b) {
  f32x4 o;
#pragma unroll
  for (int j = 0; j < 4; ++j) o[j] = fmaxf(a[j] + b[j], 0.f);
  return o;
}

// ---------------------------------------------------------------------------
__global__ void k_init(float* __restrict__ ws) {
  int t = blockIdx.x * 256 + threadIdx.x;
  int stride = gridDim.x * 256;
  for (int i = t; i < 130 * NN; i += stride)
    ws[i] = (i >= NN && i < 2 * NN) ? 1.0f : 0.0f;
}

// ---------------------------------------------------------------------------
__global__ void k_scatter(const int* __restrict__ ei, const float* __restrict__ ea,
                          float* __restrict__ deg, float* __restrict__ dout,
                          float* __restrict__ sum_in, float* __restrict__ sum_src) {
  int t = blockIdx.x * 256 + threadIdx.x;
  if (t >= EE * 64) return;
  int e = t >> 6, f = t & 63;
  int s = ei[e];
  int d = ei[EE + e];
  float v = ea[t];
  atomicAdd(&sum_in[d * 64 + f], v);
  atomicAdd(&sum_src[s * 64 + f], v);
  if (f == 0) {
    atomicAdd(&deg[d], 1.0f);
    atomicAdd(&dout[s], 1.0f);
  }
}

// ---------------------------------------------------------------------------
// Parallel prep: block c (64 blocks), lane f. Cg[c]=sum_f g1[f]W5[f][c];
// Cb[c]=sum_f b1[f]W5[f][c]; W5Thi[c][f] = bf16_rne(W5[f][c]).
__global__ void k_prep(const float* __restrict__ W5, const float* __restrict__ g1,
                       const float* __restrict__ b1, float* __restrict__ Cg,
                       float* __restrict__ Cb, unsigned short* __restrict__ W5Thi) {
  const int c = blockIdx.x;
  const int f = threadIdx.x;  // 64 threads
  float w = W5[f * 64 + c];
  unsigned int bits = __float_as_uint(w);
  // round-to-nearest-even bf16 (done once; halves quantization err vs trunc)
  unsigned int rne = bits + 0x7FFFu + ((bits >> 16) & 1u);
  W5Thi[c * 64 + f] = (unsigned short)(rne >> 16);
  float cg = g1[f] * w;
  float cb = b1[f] * w;
#pragma unroll
  for (int off = 1; off < 64; off <<= 1) {
    cg += __shfl_xor(cg, off, 64);
    cb += __shfl_xor(cb, off, 64);
  }
  if (f == 0) {
    Cg[c] = cg;
    Cb[c] = cb;
  }
}

// ---------------------------------------------------------------------------
__global__ __launch_bounds__(256) void k_rowmm(const float* __restrict__ in,
                                               const float* __restrict__ W,
                                               float* __restrict__ out, int rows) {
  const int lane = threadIdx.x & 63;
  const int wv = rfl(threadIdx.x >> 6);
  float w[64];
#pragma unroll
  for (int f = 0; f < 64; ++f) w[f] = W[f * 64 + lane];
  const int nw = gridDim.x * 4;
  for (int r = blockIdx.x * 4 + wv; r < rows; r += nw) {
    const float* xr = in + (size_t)r * 64;
    float a0 = 0, a1 = 0, a2 = 0, a3 = 0;
#pragma unroll
    for (int f = 0; f < 64; f += 4) {
      a0 = fmaf(xr[f], w[f], a0);
      a1 = fmaf(xr[f + 1], w[f + 1], a1);
      a2 = fmaf(xr[f + 2], w[f + 2], a2);
      a3 = fmaf(xr[f + 3], w[f + 3], a3);
    }
    out[(size_t)r * 64 + lane] = (a0 + a1) + (a2 + a3);
  }
}

// ---------------------------------------------------------------------------
__global__ __launch_bounds__(256) void k_xsrc(const float* __restrict__ x,
                                              const float* __restrict__ Wsrc,
                                              float* __restrict__ xsrc) {
  const int h = blockIdx.y;
  const int lane = threadIdx.x & 63;
  const int wv = rfl(threadIdx.x >> 6);
  float w[64];
#pragma unroll
  for (int f = 0; f < 64; ++f) w[f] = Wsrc[f * 640 + h * 64 + lane];
  const int nw = gridDim.x * 4;
  for (int n = blockIdx.x * 4 + wv; n < NN; n += nw) {
    const float* xr = x + (size_t)n * 64;
    float a0 = 0, a1 = 0, a2 = 0, a3 = 0;
#pragma unroll
    for (int f = 0; f < 64; f += 4) {
      a0 = fmaf(xr[f], w[f], a0);
      a1 = fmaf(xr[f + 1], w[f + 1], a1);
      a2 = fmaf(xr[f + 2], w[f + 2], a2);
      a3 = fmaf(xr[f + 3], w[f + 3], a3);
    }
    xsrc[(size_t)n * 640 + h * 64 + lane] = (a0 + a1) + (a2 + a3);
  }
}

// ---------------------------------------------------------------------------
__global__ __launch_bounds__(256) void k_eaqkv(const float* __restrict__ deg,
                                               const float* __restrict__ sum_in,
                                               const float* __restrict__ sum_src,
                                               const float* __restrict__ Wek,
                                               const float* __restrict__ Weq,
                                               const float* __restrict__ Wev,
                                               float* __restrict__ eaQ,
                                               float* __restrict__ eaK,
                                               float* __restrict__ eaV) {
  const int lane = threadIdx.x & 63;
  const int wv = rfl(threadIdx.x >> 6);
  float wq[64], wk[64], wvv[64];
#pragma unroll
  for (int f = 0; f < 64; ++f) {
    wq[f] = Wek[f * 64 + lane];
    wk[f] = Weq[f * 64 + lane];
    wvv[f] = Wev[f * 64 + lane];
  }
  const int nw = gridDim.x * 4;
  for (int n = blockIdx.x * 4 + wv; n < NN; n += nw) {
    const float* si = sum_in + (size_t)n * 64;
    const float* ss = sum_src + (size_t)n * 64;
    const float invd = 1.0f / fmaxf(deg[n], 1.0f);
    float q0 = 0, q1 = 0, k0 = 0, k1 = 0, v0 = 0, v1 = 0;
#pragma unroll
    for (int f = 0; f < 64; f += 2) {
      float e0 = fmaf(si[f], invd, ss[f]);
      float e1 = fmaf(si[f + 1], invd, ss[f + 1]);
      q0 = fmaf(e0, wq[f], q0);
      q1 = fmaf(e1, wq[f + 1], q1);
      k0 = fmaf(e0, wk[f], k0);
      k1 = fmaf(e1, wk[f + 1], k1);
      v0 = fmaf(e0, wvv[f], v0);
      v1 = fmaf(e1, wvv[f + 1], v1);
    }
    eaQ[(size_t)n * 64 + lane] = q0 + q1;
    eaK[(size_t)n * 64 + lane] = k0 + k1;
    eaV[(size_t)n * 64 + lane] = v0 + v1;
  }
}

// ---------------------------------------------------------------------------
__global__ __launch_bounds__(256) void k_qk(const float* __restrict__ xsrc,
                                            const float* __restrict__ Wnq,
                                            const float* __restrict__ Wnk,
                                            const float* __restrict__ eaQ,
                                            const float* __restrict__ eaK,
                                            const float* __restrict__ dout,
                                            float* __restrict__ qk) {
  const int lane = threadIdx.x & 63;
  const int wv = rfl(threadIdx.x >> 6);
  float wq[64], wk[64];
#pragma unroll
  for (int f = 0; f < 64; ++f) {
    wq[f] = Wnq[f * 64 + lane];
    wk[f] = Wnk[f * 64 + lane];
  }
  const int nw = gridDim.x * 4;
  for (int r = blockIdx.x * 4 + wv; r < NN * HH; r += nw) {
    int n = r / HH;
    const float* xr = xsrc + (size_t)r * 64;
    float q0 = 0, q1 = 0, k0 = 0, k1 = 0;
#pragma unroll
    for (int f = 0; f < 64; f += 2) {
      q0 = fmaf(xr[f], wq[f], q0);
      q1 = fmaf(xr[f + 1], wq[f + 1], q1);
      k0 = fmaf(xr[f], wk[f], k0);
      k1 = fmaf(xr[f + 1], wk[f + 1], k1);
    }
    float Q = (q0 + q1) + eaQ[(size_t)n * 64 + lane];
    float K = fmaf(dout[n], k0 + k1, eaK[(size_t)n * 64 + lane]);
    float p = Q * K;
#pragma unroll
    for (int off = 32; off; off >>= 1) p += __shfl_xor(p, off, 64);
    if (lane == 0) qk[r] = p * 0.125f;
  }
}

// ---------------------------------------------------------------------------
// node_update + node_out + NB, with softmax-over-heads fused (reads raw qk).
__global__ __launch_bounds__(256) void k_update(const float* __restrict__ xsrc,
                                                const float* __restrict__ Wnv,
                                                const float* __restrict__ W4,
                                                const float* __restrict__ eaV,
                                                const float* __restrict__ dout,
                                                const float* __restrict__ qk,
                                                const float* __restrict__ bias,
                                                float* __restrict__ node_out,
                                                float* __restrict__ NB) {
  __shared__ float lds[4][64];
  const int lane = threadIdx.x & 63;
  const int wv = rfl(threadIdx.x >> 6);
  float wvv[64], w4b[64];
#pragma unroll
  for (int f = 0; f < 64; ++f) {
    wvv[f] = Wnv[f * 64 + lane];
    w4b[f] = W4[(64 + f) * 64 + lane];
  }
  const int nw = gridDim.x * 4;
  for (int r = blockIdx.x * 4 + wv; r < NN * HH; r += nw) {
    int n = r / HH;
    int h = r - n * HH;
    // fused softmax over heads (wave-uniform values)
    const float* qn = qk + n * HH;
    float mx = -1e30f;
#pragma unroll
    for (int hh = 0; hh < HH; ++hh) mx = fmaxf(mx, qn[hh]);
    float den = 0.f;
#pragma unroll
    for (int hh = 0; hh < HH; ++hh) den += expf(qn[hh] - mx);
    const float wgt = expf(qn[h] - mx) / den;

    const float* xr = xsrc + (size_t)r * 64;
    float a0 = 0, a1 = 0, a2 = 0, a3 = 0;
#pragma unroll
    for (int f = 0; f < 64; f += 4) {
      a0 = fmaf(xr[f], wvv[f], a0);
      a1 = fmaf(xr[f + 1], wvv[f + 1], a1);
      a2 = fmaf(xr[f + 2], wvv[f + 2], a2);
      a3 = fmaf(xr[f + 3], wvv[f + 3], a3);
    }
    float V = fmaf(dout[n], (a0 + a1) + (a2 + a3), eaV[(size_t)n * 64 + lane]);
    float nu = xr[lane] * wgt * V;
    node_out[(size_t)r * 64 + lane] = nu + bias[h * 64 + lane];
    lds[wv][lane] = nu;
    float b0 = 0, b1 = 0, b2 = 0, b3 = 0;
#pragma unroll
    for (int k = 0; k < 64; k += 4) {
      float4 m4 = *reinterpret_cast<const float4*>(&lds[wv][k]);
      b0 = fmaf(m4.x, w4b[k], b0);
      b1 = fmaf(m4.y, w4b[k + 1], b1);
      b2 = fmaf(m4.z, w4b[k + 2], b2);
      b3 = fmaf(m4.w, w4b[k + 3], b3);
    }
    NB[(size_t)r * 64 + lane] = (b0 + b1) + (b2 + b3);
  }
}

// ---------------------------------------------------------------------------
// Edge MLP v8 (pure-bf16 MFMA, fp32 accumulate): wave = 16 edges, 10-head loop.
// D[c][r] = sum_f W5T[c][f]*m[r][f]; A = bf16(W5^T) frags resident, B = bf16(m)
// packed from per-lane global loads. Error budget: bf16 quant ~0.2-0.4% of
// intermediates, LN-invariant => final abs err ~0.05-0.2 vs threshold 0.67.
__global__ __launch_bounds__(256) void k_edge5(
    const int* __restrict__ ei, const float* __restrict__ ea_g,
    const float* __restrict__ NB, const float* __restrict__ AT,
    const unsigned short* __restrict__ W5Thi, const float* __restrict__ Cgp,
    const float* __restrict__ Cbp, const float* __restrict__ g1v,
    const float* __restrict__ g2v, const float* __restrict__ bias2,
    float* __restrict__ edge_out) {
  const int lane = threadIdx.x & 63;
  const int wv = rfl((int)threadIdx.x >> 6);
  const int g = lane >> 4;
  const int r = lane & 15;
  const int e = (blockIdx.x * 4 + wv) * 16 + r;
  const int src = ei[e];

  // A-operand frags: lane holds W5T[16*mt + r][32*ks + 8*g + i], i=0..7
  bf16x8 whi[4][2];
#pragma unroll
  for (int mt = 0; mt < 4; ++mt)
#pragma unroll
    for (int ks = 0; ks < 2; ++ks)
      whi[mt][ks] =
          *reinterpret_cast<const bf16x8*>(W5Thi + (16 * mt + r) * 64 + 32 * ks + 8 * g);

  const float* ATr = AT + (size_t)e * 64 + 8 * g;
  f32x4 at0 = *reinterpret_cast<const f32x4*>(ATr);
  f32x4 at1 = *reinterpret_cast<const f32x4*>(ATr + 4);
  f32x4 at2 = *reinterpret_cast<const f32x4*>(ATr + 32);
  f32x4 at3 = *reinterpret_cast<const f32x4*>(ATr + 36);
  const float* EAr = ea_g + (size_t)e * 64;
  const float* NBr = NB + (size_t)src * 640 + 8 * g;

  const int l0 = (((2 * g) & 3) << 4) | r;      // source lane for i<4
  const int l1 = (((2 * g + 1) & 3) << 4) | r;  // source lane for i>=4
  const bool hiHalf = (g >= 2);

  f32x4 outacc[4] = {{0, 0, 0, 0}, {0, 0, 0, 0}, {0, 0, 0, 0}, {0, 0, 0, 0}};

#pragma unroll 1
  for (int h = 0; h < HH; ++h) {
    // ---- B1 frags: m[r][f] = relu(AT[e][f] + NB[src,h][f]), f = 32ks+8g+i
    const float* nb = NBr + h * 64;
    bf16x8 mhi0 = pack8(relu4(at0, *reinterpret_cast<const f32x4*>(nb)),
                        relu4(at1, *reinterpret_cast<const f32x4*>(nb + 4)));
    bf16x8 mhi1 = pack8(relu4(at2, *reinterpret_cast<const f32x4*>(nb + 32)),
                        relu4(at3, *reinterpret_cast<const f32x4*>(nb + 36)));

    // ---- MFMA1: acc1 = ea + m @ W5 (transposed: D[c][r])
    f32x4 acc1[4];
#pragma unroll
    for (int mt = 0; mt < 4; ++mt) {
      f32x4 a = *reinterpret_cast<const f32x4*>(EAr + 16 * mt + 4 * g);
      a = __builtin_amdgcn_mfma_f32_16x16x32_bf16(whi[mt][0], mhi0, a, 0, 0, 0);
      a = __builtin_amdgcn_mfma_f32_16x16x32_bf16(whi[mt][1], mhi1, a, 0, 0, 0);
      acc1[mt] = a;
    }

    // ---- LN1 stats for row r (spread across lanes r, r+16, r+32, r+48)
    float s = 0.f, s2 = 0.f;
#pragma unroll
    for (int mt = 0; mt < 4; ++mt)
#pragma unroll
      for (int q = 0; q < 4; ++q) {
        float v = acc1[mt][q];
        s += v;
        s2 = fmaf(v, v, s2);
      }
    s += __shfl_xor(s, 16, 64);
    s2 += __shfl_xor(s2, 16, 64);
    s += __shfl_xor(s, 32, 64);
    s2 += __shfl_xor(s2, 32, 64);
    const float mu1 = s * 0.015625f;
    const float rs1 = rsqrtf(fmaxf(s2 * 0.015625f - mu1 * mu1, 1e-30f));

    // ---- exchange to B2 frags: lane (g,r) needs u_s[r][f], f=32ks+8g+i.
    // f's tile mt = 2ks + (g>=2); source lane g' = 2(g&1)+(i>>2). Shuffle both
    // tiles from source, select with DEST's hiHalf (r7 lesson).
    f32x4 us[4];
#pragma unroll
    for (int mt = 0; mt < 4; ++mt) {
      f32x4 gv = *reinterpret_cast<const f32x4*>(g1v + 16 * mt + 4 * g);
      us[mt] = acc1[mt] * gv * rs1;
    }
    float vv[16];
#pragma unroll
    for (int ks = 0; ks < 2; ++ks)
#pragma unroll
      for (int i = 0; i < 8; ++i) {
        const int sl = (i < 4) ? l0 : l1;
        float vlo = __shfl(us[2 * ks][i & 3], sl, 64);
        float vhi = __shfl(us[2 * ks + 1][i & 3], sl, 64);
        vv[ks * 8 + i] = hiHalf ? vhi : vlo;
      }
    f32x4 q0 = {vv[0], vv[1], vv[2], vv[3]};
    f32x4 q1 = {vv[4], vv[5], vv[6], vv[7]};
    f32x4 q2 = {vv[8], vv[9], vv[10], vv[11]};
    f32x4 q3 = {vv[12], vv[13], vv[14], vv[15]};
    bf16x8 bhi0 = pack8(q0, q1);
    bf16x8 bhi1 = pack8(q2, q3);

    // ---- MFMA2: acc2 = (ea + Cb - mu1*rs1*Cg) + (u*g1*rs1) @ W5
    const float m1r1 = mu1 * rs1;
    f32x4 acc2[4];
#pragma unroll
    for (int mt = 0; mt < 4; ++mt) {
      f32x4 eav = *reinterpret_cast<const f32x4*>(EAr + 16 * mt + 4 * g);
      f32x4 cbv = *reinterpret_cast<const f32x4*>(Cbp + 16 * mt + 4 * g);
      f32x4 cgv = *reinterpret_cast<const f32x4*>(Cgp + 16 * mt + 4 * g);
      f32x4 a = eav + cbv - m1r1 * cgv;
      a = __builtin_amdgcn_mfma_f32_16x16x32_bf16(whi[mt][0], bhi0, a, 0, 0, 0);
      a = __builtin_amdgcn_mfma_f32_16x16x32_bf16(whi[mt][1], bhi1, a, 0, 0, 0);
      acc2[mt] = a;
    }

    // ---- LN2 + head accumulation
    float t = 0.f, t2 = 0.f;
#pragma unroll
    for (int mt = 0; mt < 4; ++mt)
#pragma unroll
      for (int q = 0; q < 4; ++q) {
        float v = acc2[mt][q];
        t += v;
        t2 = fmaf(v, v, t2);
      }
    t += __shfl_xor(t, 16, 64);
    t2 += __shfl_xor(t2, 16, 64);
    t += __shfl_xor(t, 32, 64);
    t2 += __shfl_xor(t2, 32, 64);
    const float mu2 = t * 0.015625f;
    const float rs2 = rsqrtf(fmaxf(t2 * 0.015625f - mu2 * mu2, 1e-30f));
#pragma unroll
    for (int mt = 0; mt < 4; ++mt) {
      f32x4 g2f = *reinterpret_cast<const f32x4*>(g2v + 16 * mt + 4 * g);
      f32x4 b2f = *reinterpret_cast<const f32x4*>(bias2 + 16 * mt + 4 * g);
      outacc[mt] += (acc2[mt] - mu2) * rs2 * g2f + b2f;
    }
  }

#pragma unroll
  for (int mt = 0; mt < 4; ++mt) {
    f32x4 o = outacc[mt] * 0.1f;
    *reinterpret_cast<f32x4*>(edge_out + (size_t)e * 64 + 16 * mt + 4 * g) = o;
  }
}

// ---------------------------------------------------------------------------
extern "C" void kernel_launch(void* const* d_in, const int* in_sizes, int n_in,
                              void* d_out, int out_size, void* d_ws, size_t ws_size,
                              hipStream_t stream) {
  const float* x = (const float*)d_in[0];
  const int* ei = (const int*)d_in[1];
  const float* edge_attr = (const float*)d_in[2];
  const float* W_src = (const float*)d_in[3];
  const float* Wnq = (const float*)d_in[4];
  const float* Wnk = (const float*)d_in[5];
  const float* Wnv = (const float*)d_in[6];
  const float* Weq = (const float*)d_in[7];
  const float* Wev = (const float*)d_in[8];
  const float* Wek = (const float*)d_in[9];
  const float* W4 = (const float*)d_in[10];
  const float* W5 = (const float*)d_in[11];
  const float* g1 = (const float*)d_in[12];
  const float* b1 = (const float*)d_in[13];
  const float* g2 = (const float*)d_in[14];
  const float* b2 = (const float*)d_in[15];
  const float* bias = (const float*)d_in[16];
  (void)in_sizes; (void)n_in; (void)out_size; (void)ws_size;

  float* ws = (float*)d_ws;
  float* deg = ws;
  float* dout = ws + NN;
  float* sum_in = ws + 2 * NN;
  float* sum_src = ws + 66 * NN;
  unsigned short* W5Thi = (unsigned short*)(ws + 130 * NN);
  float* eaQ = ws + 194 * NN;
  float* eaK = ws + 258 * NN;
  float* eaV = ws + 322 * NN;
  float* xsrc = ws + 386 * NN;
  float* NB = ws + 1026 * NN;
  float* qk = ws + 1666 * NN;
  float* A = ws + 1686 * NN;
  float* Cg = ws + 1686 * NN + 64 * EE;
  float* Cb = Cg + 64;

  float* node_out = (float*)d_out;
  float* edge_out = (float*)d_out + (size_t)NN * 640;

  k_init<<<1024, 256, 0, stream>>>(ws);
  k_prep<<<64, 64, 0, stream>>>(W5, g1, b1, Cg, Cb, W5Thi);
  k_scatter<<<EE * 64 / 256, 256, 0, stream>>>(ei, edge_attr, deg, dout, sum_in, sum_src);
  k_rowmm<<<1024, 256, 0, stream>>>(edge_attr, W4, A, EE);  // A = ea @ W4_top
  k_xsrc<<<dim3(256, 10), 256, 0, stream>>>(x, W_src, xsrc);
  k_eaqkv<<<250, 256, 0, stream>>>(deg, sum_in, sum_src, Wek, Weq, Wev, eaQ, eaK, eaV);
  k_qk<<<1024, 256, 0, stream>>>(xsrc, Wnq, Wnk, eaQ, eaK, dout, qk);
  k_update<<<1024, 256, 0, stream>>>(xsrc, Wnv, W4, eaV, dout, qk, bias, node_out, NB);
  k_edge5<<<EE / 64, 256, 0, stream>>>(ei, edge_attr, NB, A, W5Thi, Cg, Cb, g1, g2, b2,
                                       edge_out);
}

// Round 11
// 188.032 us; speedup vs baseline: 1.6853x; 1.6853x over previous
//
#include <hip/hip_runtime.h>
#include <cstdint>
#include <cstddef>

#define NN 8000
#define EE 64000
#define HH 10

// wbuf (unsigned short) offsets
#define OFF_W5T 0
#define OFF_WNQ 4096
#define OFF_WNQL 8192
#define OFF_WNK 12288
#define OFF_WNKL 16384
#define OFF_WNV 20480
#define OFF_WNVL 24576
#define OFF_W4B 28672
#define OFF_W4T 32768
#define OFF_WSRC 36864
#define OFF_WSRCL 77824
// total 118784 shorts = 59392 floats (< 64*NN region)

typedef __attribute__((ext_vector_type(8))) short bf16x8;
typedef __attribute__((ext_vector_type(4))) float f32x4;
typedef __attribute__((ext_vector_type(4))) unsigned int u32x4;

__device__ __forceinline__ int rfl(int v) { return __builtin_amdgcn_readfirstlane(v); }

__device__ __forceinline__ unsigned int rne16(float w) {
  unsigned int b = __float_as_uint(w);
  return (b + 0x7FFFu + ((b >> 16) & 1u)) >> 16;
}

// ---- pack 8 consecutive f32 into one bf16x8 (truncation)
__device__ __forceinline__ bf16x8 pack8(f32x4 a, f32x4 b) {
  u32x4 u;
  u[0] = (__float_as_uint(a[1]) & 0xFFFF0000u) | (__float_as_uint(a[0]) >> 16);
  u[1] = (__float_as_uint(a[3]) & 0xFFFF0000u) | (__float_as_uint(a[2]) >> 16);
  u[2] = (__float_as_uint(b[1]) & 0xFFFF0000u) | (__float_as_uint(b[0]) >> 16);
  u[3] = (__float_as_uint(b[3]) & 0xFFFF0000u) | (__float_as_uint(b[2]) >> 16);
  return __builtin_bit_cast(bf16x8, u);
}

// ---- hi/lo split: hi=trunc bf16, lo=bf16(residual); 3-term MFMA err ~2^-16
__device__ __forceinline__ void split8(f32x4 a, f32x4 b, bf16x8& hi, bf16x8& lo) {
  unsigned int h[4], l[4];
#pragma unroll
  for (int j = 0; j < 2; ++j) {
    unsigned int b0 = __float_as_uint(a[2 * j]);
    unsigned int b1 = __float_as_uint(a[2 * j + 1]);
    h[j] = (b1 & 0xFFFF0000u) | (b0 >> 16);
    float r0 = a[2 * j] - __uint_as_float(b0 & 0xFFFF0000u);
    float r1 = a[2 * j + 1] - __uint_as_float(b1 & 0xFFFF0000u);
    l[j] = (__float_as_uint(r1) & 0xFFFF0000u) | (__float_as_uint(r0) >> 16);
  }
#pragma unroll
  for (int j = 0; j < 2; ++j) {
    unsigned int b0 = __float_as_uint(b[2 * j]);
    unsigned int b1 = __float_as_uint(b[2 * j + 1]);
    h[2 + j] = (b1 & 0xFFFF0000u) | (b0 >> 16);
    float r0 = b[2 * j] - __uint_as_float(b0 & 0xFFFF0000u);
    float r1 = b[2 * j + 1] - __uint_as_float(b1 & 0xFFFF0000u);
    l[2 + j] = (__float_as_uint(r1) & 0xFFFF0000u) | (__float_as_uint(r0) >> 16);
  }
  u32x4 uh = {h[0], h[1], h[2], h[3]};
  u32x4 ul = {l[0], l[1], l[2], l[3]};
  hi = __builtin_bit_cast(bf16x8, uh);
  lo = __builtin_bit_cast(bf16x8, ul);
}

__device__ __forceinline__ f32x4 relu4(f32x4 a, f32x4 b) {
  f32x4 o;
#pragma unroll
  for (int j = 0; j < 4; ++j) o[j] = fmaxf(a[j] + b[j], 0.f);
  return o;
}

// ---------------------------------------------------------------------------
__global__ void k_init(float* __restrict__ ws) {
  int t = blockIdx.x * 256 + threadIdx.x;
  int stride = gridDim.x * 256;
  for (int i = t; i < 130 * NN; i += stride)
    ws[i] = (i >= NN && i < 2 * NN) ? 1.0f : 0.0f;
}

// ---------------------------------------------------------------------------
__global__ void k_scatter(const int* __restrict__ ei, const float* __restrict__ ea,
                          float* __restrict__ deg, float* __restrict__ dout,
                          float* __restrict__ sum_in, float* __restrict__ sum_src) {
  int t = blockIdx.x * 256 + threadIdx.x;
  if (t >= EE * 64) return;
  int e = t >> 6, f = t & 63;
  int s = ei[e];
  int d = ei[EE + e];
  float v = ea[t];
  atomicAdd(&sum_in[d * 64 + f], v);
  atomicAdd(&sum_src[s * 64 + f], v);
  if (f == 0) {
    atomicAdd(&deg[d], 1.0f);
    atomicAdd(&dout[s], 1.0f);
  }
}

// ---------------------------------------------------------------------------
__global__ void k_prep(const float* __restrict__ W5, const float* __restrict__ g1,
                       const float* __restrict__ b1, float* __restrict__ Cg,
                       float* __restrict__ Cb, unsigned short* __restrict__ wbuf) {
  const int c = blockIdx.x;
  const int f = threadIdx.x;  // 64 threads
  float w = W5[f * 64 + c];
  wbuf[OFF_W5T + c * 64 + f] = (unsigned short)rne16(w);
  float cg = g1[f] * w;
  float cb = b1[f] * w;
#pragma unroll
  for (int off = 1; off < 64; off <<= 1) {
    cg += __shfl_xor(cg, off, 64);
    cb += __shfl_xor(cb, off, 64);
  }
  if (f == 0) {
    Cg[c] = cg;
    Cb[c] = cb;
  }
}

// ---------------------------------------------------------------------------
// Transposed weights, hi(+lo for precision-critical) bf16.
// y: 0=Wnq 1=Wnk 2=Wnv 3=W4bot 4=W4top 5..14=Wsrc head h=y-5
__global__ void k_prepw(const float* __restrict__ Wnq, const float* __restrict__ Wnk,
                        const float* __restrict__ Wnv, const float* __restrict__ W4,
                        const float* __restrict__ Wsrc, unsigned short* __restrict__ wbuf) {
  const int c = blockIdx.x, f = threadIdx.x, y = blockIdx.y;
  float w;
  int hioff, looff = -1;
  const int cf = c * 64 + f;
  if (y == 0) { w = Wnq[f * 64 + c]; hioff = OFF_WNQ + cf; looff = OFF_WNQL + cf; }
  else if (y == 1) { w = Wnk[f * 64 + c]; hioff = OFF_WNK + cf; looff = OFF_WNKL + cf; }
  else if (y == 2) { w = Wnv[f * 64 + c]; hioff = OFF_WNV + cf; looff = OFF_WNVL + cf; }
  else if (y == 3) { w = W4[(64 + f) * 64 + c]; hioff = OFF_W4B + cf; }
  else if (y == 4) { w = W4[f * 64 + c]; hioff = OFF_W4T + cf; }
  else {
    int h = y - 5;
    w = Wsrc[f * 640 + h * 64 + c];
    hioff = OFF_WSRC + (h * 64 + c) * 64 + f;
    looff = OFF_WSRCL + (h * 64 + c) * 64 + f;
  }
  unsigned int hi = rne16(w);
  wbuf[hioff] = (unsigned short)hi;
  if (looff >= 0) {
    float rest = w - __uint_as_float(hi << 16);
    wbuf[looff] = (unsigned short)rne16(rest);
  }
}

// ---------------------------------------------------------------------------
// A_ws = ea @ W4top via pure-bf16 MFMA (LN-protected downstream).
__global__ __launch_bounds__(256) void k_am(const float* __restrict__ ea,
                                            const unsigned short* __restrict__ wbuf,
                                            float* __restrict__ A) {
  const int lane = threadIdx.x & 63;
  const int wv = rfl((int)threadIdx.x >> 6);
  const int g = lane >> 4, r = lane & 15;
  const int e = (blockIdx.x * 4 + wv) * 16 + r;
  bf16x8 wa[4][2];
#pragma unroll
  for (int mt = 0; mt < 4; ++mt)
#pragma unroll
    for (int ks = 0; ks < 2; ++ks)
      wa[mt][ks] = *reinterpret_cast<const bf16x8*>(wbuf + OFF_W4T + (16 * mt + r) * 64 +
                                                    32 * ks + 8 * g);
  const float* er = ea + (size_t)e * 64 + 8 * g;
  bf16x8 xb0 = pack8(*reinterpret_cast<const f32x4*>(er), *reinterpret_cast<const f32x4*>(er + 4));
  bf16x8 xb1 = pack8(*reinterpret_cast<const f32x4*>(er + 32), *reinterpret_cast<const f32x4*>(er + 36));
#pragma unroll
  for (int mt = 0; mt < 4; ++mt) {
    f32x4 d = {0, 0, 0, 0};
    d = __builtin_amdgcn_mfma_f32_16x16x32_bf16(wa[mt][0], xb0, d, 0, 0, 0);
    d = __builtin_amdgcn_mfma_f32_16x16x32_bf16(wa[mt][1], xb1, d, 0, 0, 0);
    *reinterpret_cast<f32x4*>(A + (size_t)e * 64 + 16 * mt + 4 * g) = d;
  }
}

// ---------------------------------------------------------------------------
// xsrc[(n*10+h)*64+c] = sum_f x[n][f]*Wsrc[f][h*64+c], 3-term hi/lo (fp32-level).
__global__ __launch_bounds__(256) void k_xsrcm(const float* __restrict__ x,
                                               const unsigned short* __restrict__ wbuf,
                                               float* __restrict__ xsrc) {
  const int lane = threadIdx.x & 63;
  const int wv = rfl((int)threadIdx.x >> 6);
  const int g = lane >> 4, r = lane & 15;
  const int h = blockIdx.y;
  const int n = (blockIdx.x * 4 + wv) * 16 + r;  // grid.x exact: NN/64
  bf16x8 whi[4][2], wlo[4][2];
#pragma unroll
  for (int mt = 0; mt < 4; ++mt)
#pragma unroll
    for (int ks = 0; ks < 2; ++ks) {
      const int off = (h * 64 + 16 * mt + r) * 64 + 32 * ks + 8 * g;
      whi[mt][ks] = *reinterpret_cast<const bf16x8*>(wbuf + OFF_WSRC + off);
      wlo[mt][ks] = *reinterpret_cast<const bf16x8*>(wbuf + OFF_WSRCL + off);
    }
  const float* xr = x + (size_t)n * 64 + 8 * g;
  bf16x8 xh0, xl0, xh1, xl1;
  split8(*reinterpret_cast<const f32x4*>(xr), *reinterpret_cast<const f32x4*>(xr + 4), xh0, xl0);
  split8(*reinterpret_cast<const f32x4*>(xr + 32), *reinterpret_cast<const f32x4*>(xr + 36), xh1, xl1);
  const size_t base = ((size_t)n * 10 + h) * 64;
#pragma unroll
  for (int mt = 0; mt < 4; ++mt) {
    f32x4 d = {0, 0, 0, 0};
    d = __builtin_amdgcn_mfma_f32_16x16x32_bf16(whi[mt][0], xh0, d, 0, 0, 0);
    d = __builtin_amdgcn_mfma_f32_16x16x32_bf16(whi[mt][1], xh1, d, 0, 0, 0);
    d = __builtin_amdgcn_mfma_f32_16x16x32_bf16(whi[mt][0], xl0, d, 0, 0, 0);
    d = __builtin_amdgcn_mfma_f32_16x16x32_bf16(whi[mt][1], xl1, d, 0, 0, 0);
    d = __builtin_amdgcn_mfma_f32_16x16x32_bf16(wlo[mt][0], xh0, d, 0, 0, 0);
    d = __builtin_amdgcn_mfma_f32_16x16x32_bf16(wlo[mt][1], xh1, d, 0, 0, 0);
    *reinterpret_cast<f32x4*>(xsrc + base + 16 * mt + 4 * g) = d;
  }
}

// ---------------------------------------------------------------------------
__global__ __launch_bounds__(256) void k_eaqkv(const float* __restrict__ deg,
                                               const float* __restrict__ sum_in,
                                               const float* __restrict__ sum_src,
                                               const float* __restrict__ Wek,
                                               const float* __restrict__ Weq,
                                               const float* __restrict__ Wev,
                                               float* __restrict__ eaQ,
                                               float* __restrict__ eaK,
                                               float* __restrict__ eaV) {
  const int lane = threadIdx.x & 63;
  const int wv = rfl(threadIdx.x >> 6);
  float wq[64], wk[64], wvv[64];
#pragma unroll
  for (int f = 0; f < 64; ++f) {
    wq[f] = Wek[f * 64 + lane];
    wk[f] = Weq[f * 64 + lane];
    wvv[f] = Wev[f * 64 + lane];
  }
  const int nw = gridDim.x * 4;
  for (int n = blockIdx.x * 4 + wv; n < NN; n += nw) {
    const float* si = sum_in + (size_t)n * 64;
    const float* ss = sum_src + (size_t)n * 64;
    const float invd = 1.0f / fmaxf(deg[n], 1.0f);
    float q0 = 0, q1 = 0, k0 = 0, k1 = 0, v0 = 0, v1 = 0;
#pragma unroll
    for (int f = 0; f < 64; f += 2) {
      float e0 = fmaf(si[f], invd, ss[f]);
      float e1 = fmaf(si[f + 1], invd, ss[f + 1]);
      q0 = fmaf(e0, wq[f], q0);
      q1 = fmaf(e1, wq[f + 1], q1);
      k0 = fmaf(e0, wk[f], k0);
      k1 = fmaf(e1, wk[f + 1], k1);
      v0 = fmaf(e0, wvv[f], v0);
      v1 = fmaf(e1, wvv[f + 1], v1);
    }
    eaQ[(size_t)n * 64 + lane] = q0 + q1;
    eaK[(size_t)n * 64 + lane] = k0 + k1;
    eaV[(size_t)n * 64 + lane] = v0 + v1;
  }
}

// ---------------------------------------------------------------------------
// qk via 3-term hi/lo MFMA projections + exact f32 eaQ/eaK + in-register dot.
__global__ __launch_bounds__(256) void k_qkm(const float* __restrict__ xsrc,
                                             const unsigned short* __restrict__ wbuf,
                                             const float* __restrict__ eaQ,
                                             const float* __restrict__ eaK,
                                             const float* __restrict__ dout,
                                             float* __restrict__ qk) {
  const int lane = threadIdx.x & 63;
  const int wv = rfl((int)threadIdx.x >> 6);
  const int g = lane >> 4, r = lane & 15;
  const int r0 = (blockIdx.x * 4 + wv) * 16;  // grid exact: NN*HH/64
  const int grow = r0 + r;
  const int n = grow / 10;
  const float* xp = xsrc + (size_t)grow * 64 + 8 * g;
  bf16x8 xh0, xl0, xh1, xl1;
  split8(*reinterpret_cast<const f32x4*>(xp), *reinterpret_cast<const f32x4*>(xp + 4), xh0, xl0);
  split8(*reinterpret_cast<const f32x4*>(xp + 32), *reinterpret_cast<const f32x4*>(xp + 36), xh1, xl1);
  const float dn = dout[n];
  f32x4 qf[4];
#pragma unroll
  for (int mt = 0; mt < 4; ++mt) {
    const int off = (16 * mt + r) * 64 + 8 * g;
    bf16x8 ah0 = *reinterpret_cast<const bf16x8*>(wbuf + OFF_WNQ + off);
    bf16x8 ah1 = *reinterpret_cast<const bf16x8*>(wbuf + OFF_WNQ + off + 32);
    bf16x8 al0 = *reinterpret_cast<const bf16x8*>(wbuf + OFF_WNQL + off);
    bf16x8 al1 = *reinterpret_cast<const bf16x8*>(wbuf + OFF_WNQL + off + 32);
    f32x4 d = {0, 0, 0, 0};
    d = __builtin_amdgcn_mfma_f32_16x16x32_bf16(ah0, xh0, d, 0, 0, 0);
    d = __builtin_amdgcn_mfma_f32_16x16x32_bf16(ah1, xh1, d, 0, 0, 0);
    d = __builtin_amdgcn_mfma_f32_16x16x32_bf16(ah0, xl0, d, 0, 0, 0);
    d = __builtin_amdgcn_mfma_f32_16x16x32_bf16(ah1, xl1, d, 0, 0, 0);
    d = __builtin_amdgcn_mfma_f32_16x16x32_bf16(al0, xh0, d, 0, 0, 0);
    d = __builtin_amdgcn_mfma_f32_16x16x32_bf16(al1, xh1, d, 0, 0, 0);
    qf[mt] = d;
  }
  float p = 0.f;
#pragma unroll
  for (int mt = 0; mt < 4; ++mt) {
    const int off = (16 * mt + r) * 64 + 8 * g;
    bf16x8 ah0 = *reinterpret_cast<const bf16x8*>(wbuf + OFF_WNK + off);
    bf16x8 ah1 = *reinterpret_cast<const bf16x8*>(wbuf + OFF_WNK + off + 32);
    bf16x8 al0 = *reinterpret_cast<const bf16x8*>(wbuf + OFF_WNKL + off);
    bf16x8 al1 = *reinterpret_cast<const bf16x8*>(wbuf + OFF_WNKL + off + 32);
    f32x4 d = {0, 0, 0, 0};
    d = __builtin_amdgcn_mfma_f32_16x16x32_bf16(ah0, xh0, d, 0, 0, 0);
    d = __builtin_amdgcn_mfma_f32_16x16x32_bf16(ah1, xh1, d, 0, 0, 0);
    d = __builtin_amdgcn_mfma_f32_16x16x32_bf16(ah0, xl0, d, 0, 0, 0);
    d = __builtin_amdgcn_mfma_f32_16x16x32_bf16(ah1, xl1, d, 0, 0, 0);
    d = __builtin_amdgcn_mfma_f32_16x16x32_bf16(al0, xh0, d, 0, 0, 0);
    d = __builtin_amdgcn_mfma_f32_16x16x32_bf16(al1, xh1, d, 0, 0, 0);
    f32x4 eq = *reinterpret_cast<const f32x4*>(eaQ + (size_t)n * 64 + 16 * mt + 4 * g);
    f32x4 ek = *reinterpret_cast<const f32x4*>(eaK + (size_t)n * 64 + 16 * mt + 4 * g);
#pragma unroll
    for (int q = 0; q < 4; ++q) p = fmaf(qf[mt][q] + eq[q], fmaf(dn, d[q], ek[q]), p);
  }
  p += __shfl_xor(p, 16, 64);
  p += __shfl_xor(p, 32, 64);
  if (lane < 16) qk[r0 + lane] = p * 0.125f;
}

// ---------------------------------------------------------------------------
__global__ void k_softmax(const float* __restrict__ qk, float* __restrict__ sm) {
  int n = blockIdx.x * 256 + threadIdx.x;
  if (n >= NN) return;
  float v[HH];
  float mx = -1e30f;
#pragma unroll
  for (int h = 0; h < HH; ++h) {
    v[h] = qk[n * HH + h];
    mx = fmaxf(mx, v[h]);
  }
  float s = 0;
#pragma unroll
  for (int h = 0; h < HH; ++h) {
    v[h] = expf(v[h] - mx);
    s += v[h];
  }
  float inv = 1.0f / s;
#pragma unroll
  for (int h = 0; h < HH; ++h) sm[n * HH + h] = v[h] * inv;
}

// ---------------------------------------------------------------------------
// V = dout*(xsrc@Wnv)+eaV (3-term); nu = xsrc*sm*V (f32); node_out = nu+bias;
// NB = nu @ W4bot (exchange + pure-bf16 MFMA, LN-protected downstream).
__global__ __launch_bounds__(256) void k_updm(const float* __restrict__ xsrc,
                                              const unsigned short* __restrict__ wbuf,
                                              const float* __restrict__ eaV,
                                              const float* __restrict__ dout,
                                              const float* __restrict__ sm,
                                              const float* __restrict__ bias,
                                              float* __restrict__ node_out,
                                              float* __restrict__ NB) {
  const int lane = threadIdx.x & 63;
  const int wv = rfl((int)threadIdx.x >> 6);
  const int g = lane >> 4, r = lane & 15;
  const int grow = (blockIdx.x * 4 + wv) * 16 + r;  // grid exact: NN*HH/64
  const int n = grow / 10;
  const int h = grow - 10 * n;
  const float* xp = xsrc + (size_t)grow * 64;
  bf16x8 xh0, xl0, xh1, xl1;
  split8(*reinterpret_cast<const f32x4*>(xp + 8 * g), *reinterpret_cast<const f32x4*>(xp + 8 * g + 4),
         xh0, xl0);
  split8(*reinterpret_cast<const f32x4*>(xp + 8 * g + 32),
         *reinterpret_cast<const f32x4*>(xp + 8 * g + 36), xh1, xl1);
  const float dn = dout[n];
  const float wgt = sm[grow];
  f32x4 nu[4];
#pragma unroll
  for (int mt = 0; mt < 4; ++mt) {
    const int off = (16 * mt + r) * 64 + 8 * g;
    bf16x8 ah0 = *reinterpret_cast<const bf16x8*>(wbuf + OFF_WNV + off);
    bf16x8 ah1 = *reinterpret_cast<const bf16x8*>(wbuf + OFF_WNV + off + 32);
    bf16x8 al0 = *reinterpret_cast<const bf16x8*>(wbuf + OFF_WNVL + off);
    bf16x8 al1 = *reinterpret_cast<const bf16x8*>(wbuf + OFF_WNVL + off + 32);
    f32x4 vf = {0, 0, 0, 0};
    vf = __builtin_amdgcn_mfma_f32_16x16x32_bf16(ah0, xh0, vf, 0, 0, 0);
    vf = __builtin_amdgcn_mfma_f32_16x16x32_bf16(ah1, xh1, vf, 0, 0, 0);
    vf = __builtin_amdgcn_mfma_f32_16x16x32_bf16(ah0, xl0, vf, 0, 0, 0);
    vf = __builtin_amdgcn_mfma_f32_16x16x32_bf16(ah1, xl1, vf, 0, 0, 0);
    vf = __builtin_amdgcn_mfma_f32_16x16x32_bf16(al0, xh0, vf, 0, 0, 0);
    vf = __builtin_amdgcn_mfma_f32_16x16x32_bf16(al1, xh1, vf, 0, 0, 0);
    f32x4 ev = *reinterpret_cast<const f32x4*>(eaV + (size_t)n * 64 + 16 * mt + 4 * g);
    f32x4 xs = *reinterpret_cast<const f32x4*>(xp + 16 * mt + 4 * g);
    f32x4 nn;
#pragma unroll
    for (int q = 0; q < 4; ++q) nn[q] = xs[q] * wgt * fmaf(dn, vf[q], ev[q]);
    nu[mt] = nn;
    f32x4 bs = *reinterpret_cast<const f32x4*>(bias + h * 64 + 16 * mt + 4 * g);
    *reinterpret_cast<f32x4*>(node_out + (size_t)grow * 64 + 16 * mt + 4 * g) = nn + bs;
  }
  // exchange nu -> B-frags (r7-verified: shuffle both tiles, select by DEST hiHalf)
  const int l0 = (((2 * g) & 3) << 4) | r;
  const int l1 = (((2 * g + 1) & 3) << 4) | r;
  const bool hiHalf = (g >= 2);
  float vv[16];
#pragma unroll
  for (int ks = 0; ks < 2; ++ks)
#pragma unroll
    for (int i = 0; i < 8; ++i) {
      const int sl = (i < 4) ? l0 : l1;
      float vlo = __shfl(nu[2 * ks][i & 3], sl, 64);
      float vhi = __shfl(nu[2 * ks + 1][i & 3], sl, 64);
      vv[ks * 8 + i] = hiHalf ? vhi : vlo;
    }
  f32x4 q0 = {vv[0], vv[1], vv[2], vv[3]};
  f32x4 q1 = {vv[4], vv[5], vv[6], vv[7]};
  f32x4 q2 = {vv[8], vv[9], vv[10], vv[11]};
  f32x4 q3 = {vv[12], vv[13], vv[14], vv[15]};
  bf16x8 nb0 = pack8(q0, q1);
  bf16x8 nb1 = pack8(q2, q3);
#pragma unroll
  for (int mt = 0; mt < 4; ++mt) {
    const int off = (16 * mt + r) * 64 + 8 * g;
    bf16x8 ba0 = *reinterpret_cast<const bf16x8*>(wbuf + OFF_W4B + off);
    bf16x8 ba1 = *reinterpret_cast<const bf16x8*>(wbuf + OFF_W4B + off + 32);
    f32x4 nf = {0, 0, 0, 0};
    nf = __builtin_amdgcn_mfma_f32_16x16x32_bf16(ba0, nb0, nf, 0, 0, 0);
    nf = __builtin_amdgcn_mfma_f32_16x16x32_bf16(ba1, nb1, nf, 0, 0, 0);
    *reinterpret_cast<f32x4*>(NB + (size_t)grow * 64 + 16 * mt + 4 * g) = nf;
  }
}

// ---------------------------------------------------------------------------
// Edge MLP (r8/r9-verified): pure-bf16 MFMA, fp32 accumulate.
__global__ __launch_bounds__(256) void k_edge5(
    const int* __restrict__ ei, const float* __restrict__ ea_g,
    const float* __restrict__ NB, const float* __restrict__ AT,
    const unsigned short* __restrict__ wbuf, const float* __restrict__ Cgp,
    const float* __restrict__ Cbp, const float* __restrict__ g1v,
    const float* __restrict__ g2v, const float* __restrict__ bias2,
    float* __restrict__ edge_out) {
  const int lane = threadIdx.x & 63;
  const int wv = rfl((int)threadIdx.x >> 6);
  const int g = lane >> 4;
  const int r = lane & 15;
  const int e = (blockIdx.x * 4 + wv) * 16 + r;
  const int src = ei[e];

  bf16x8 whi[4][2];
#pragma unroll
  for (int mt = 0; mt < 4; ++mt)
#pragma unroll
    for (int ks = 0; ks < 2; ++ks)
      whi[mt][ks] = *reinterpret_cast<const bf16x8*>(wbuf + OFF_W5T + (16 * mt + r) * 64 +
                                                     32 * ks + 8 * g);

  const float* ATr = AT + (size_t)e * 64 + 8 * g;
  f32x4 at0 = *reinterpret_cast<const f32x4*>(ATr);
  f32x4 at1 = *reinterpret_cast<const f32x4*>(ATr + 4);
  f32x4 at2 = *reinterpret_cast<const f32x4*>(ATr + 32);
  f32x4 at3 = *reinterpret_cast<const f32x4*>(ATr + 36);
  const float* EAr = ea_g + (size_t)e * 64;
  const float* NBr = NB + (size_t)src * 640 + 8 * g;

  const int l0 = (((2 * g) & 3) << 4) | r;
  const int l1 = (((2 * g + 1) & 3) << 4) | r;
  const bool hiHalf = (g >= 2);

  f32x4 outacc[4] = {{0, 0, 0, 0}, {0, 0, 0, 0}, {0, 0, 0, 0}, {0, 0, 0, 0}};

#pragma unroll 1
  for (int h = 0; h < HH; ++h) {
    const float* nb = NBr + h * 64;
    bf16x8 mhi0 = pack8(relu4(at0, *reinterpret_cast<const f32x4*>(nb)),
                        relu4(at1, *reinterpret_cast<const f32x4*>(nb + 4)));
    bf16x8 mhi1 = pack8(relu4(at2, *reinterpret_cast<const f32x4*>(nb + 32)),
                        relu4(at3, *reinterpret_cast<const f32x4*>(nb + 36)));

    f32x4 acc1[4];
#pragma unroll
    for (int mt = 0; mt < 4; ++mt) {
      f32x4 a = *reinterpret_cast<const f32x4*>(EAr + 16 * mt + 4 * g);
      a = __builtin_amdgcn_mfma_f32_16x16x32_bf16(whi[mt][0], mhi0, a, 0, 0, 0);
      a = __builtin_amdgcn_mfma_f32_16x16x32_bf16(whi[mt][1], mhi1, a, 0, 0, 0);
      acc1[mt] = a;
    }

    float s = 0.f, s2 = 0.f;
#pragma unroll
    for (int mt = 0; mt < 4; ++mt)
#pragma unroll
      for (int q = 0; q < 4; ++q) {
        float v = acc1[mt][q];
        s += v;
        s2 = fmaf(v, v, s2);
      }
    s += __shfl_xor(s, 16, 64);
    s2 += __shfl_xor(s2, 16, 64);
    s += __shfl_xor(s, 32, 64);
    s2 += __shfl_xor(s2, 32, 64);
    const float mu1 = s * 0.015625f;
    const float rs1 = rsqrtf(fmaxf(s2 * 0.015625f - mu1 * mu1, 1e-30f));

    f32x4 us[4];
#pragma unroll
    for (int mt = 0; mt < 4; ++mt) {
      f32x4 gv = *reinterpret_cast<const f32x4*>(g1v + 16 * mt + 4 * g);
      us[mt] = acc1[mt] * gv * rs1;
    }
    float vv[16];
#pragma unroll
    for (int ks = 0; ks < 2; ++ks)
#pragma unroll
      for (int i = 0; i < 8; ++i) {
        const int sl = (i < 4) ? l0 : l1;
        float vlo = __shfl(us[2 * ks][i & 3], sl, 64);
        float vhi = __shfl(us[2 * ks + 1][i & 3], sl, 64);
        vv[ks * 8 + i] = hiHalf ? vhi : vlo;
      }
    f32x4 q0 = {vv[0], vv[1], vv[2], vv[3]};
    f32x4 q1 = {vv[4], vv[5], vv[6], vv[7]};
    f32x4 q2 = {vv[8], vv[9], vv[10], vv[11]};
    f32x4 q3 = {vv[12], vv[13], vv[14], vv[15]};
    bf16x8 bhi0 = pack8(q0, q1);
    bf16x8 bhi1 = pack8(q2, q3);

    const float m1r1 = mu1 * rs1;
    f32x4 acc2[4];
#pragma unroll
    for (int mt = 0; mt < 4; ++mt) {
      f32x4 eav = *reinterpret_cast<const f32x4*>(EAr + 16 * mt + 4 * g);
      f32x4 cbv = *reinterpret_cast<const f32x4*>(Cbp + 16 * mt + 4 * g);
      f32x4 cgv = *reinterpret_cast<const f32x4*>(Cgp + 16 * mt + 4 * g);
      f32x4 a = eav + cbv - m1r1 * cgv;
      a = __builtin_amdgcn_mfma_f32_16x16x32_bf16(whi[mt][0], bhi0, a, 0, 0, 0);
      a = __builtin_amdgcn_mfma_f32_16x16x32_bf16(whi[mt][1], bhi1, a, 0, 0, 0);
      acc2[mt] = a;
    }

    float t = 0.f, t2 = 0.f;
#pragma unroll
    for (int mt = 0; mt < 4; ++mt)
#pragma unroll
      for (int q = 0; q < 4; ++q) {
        float v = acc2[mt][q];
        t += v;
        t2 = fmaf(v, v, t2);
      }
    t += __shfl_xor(t, 16, 64);
    t2 += __shfl_xor(t2, 16, 64);
    t += __shfl_xor(t, 32, 64);
    t2 += __shfl_xor(t2, 32, 64);
    const float mu2 = t * 0.015625f;
    const float rs2 = rsqrtf(fmaxf(t2 * 0.015625f - mu2 * mu2, 1e-30f));
#pragma unroll
    for (int mt = 0; mt < 4; ++mt) {
      f32x4 g2f = *reinterpret_cast<const f32x4*>(g2v + 16 * mt + 4 * g);
      f32x4 b2f = *reinterpret_cast<const f32x4*>(bias2 + 16 * mt + 4 * g);
      outacc[mt] += (acc2[mt] - mu2) * rs2 * g2f + b2f;
    }
  }

#pragma unroll
  for (int mt = 0; mt < 4; ++mt) {
    f32x4 o = outacc[mt] * 0.1f;
    *reinterpret_cast<f32x4*>(edge_out + (size_t)e * 64 + 16 * mt + 4 * g) = o;
  }
}

// ---------------------------------------------------------------------------
extern "C" void kernel_launch(void* const* d_in, const int* in_sizes, int n_in,
                              void* d_out, int out_size, void* d_ws, size_t ws_size,
                              hipStream_t stream) {
  const float* x = (const float*)d_in[0];
  const int* ei = (const int*)d_in[1];
  const float* edge_attr = (const float*)d_in[2];
  const float* W_src = (const float*)d_in[3];
  const float* Wnq = (const float*)d_in[4];
  const float* Wnk = (const float*)d_in[5];
  const float* Wnv = (const float*)d_in[6];
  const float* Weq = (const float*)d_in[7];
  const float* Wev = (const float*)d_in[8];
  const float* Wek = (const float*)d_in[9];
  const float* W4 = (const float*)d_in[10];
  const float* W5 = (const float*)d_in[11];
  const float* g1 = (const float*)d_in[12];
  const float* b1 = (const float*)d_in[13];
  const float* g2 = (const float*)d_in[14];
  const float* b2 = (const float*)d_in[15];
  const float* bias = (const float*)d_in[16];
  (void)in_sizes; (void)n_in; (void)out_size; (void)ws_size;

  float* ws = (float*)d_ws;
  float* deg = ws;
  float* dout = ws + NN;
  float* sum_in = ws + 2 * NN;
  float* sum_src = ws + 66 * NN;
  unsigned short* wbuf = (unsigned short*)(ws + 130 * NN);
  float* eaQ = ws + 194 * NN;
  float* eaK = ws + 258 * NN;
  float* eaV = ws + 322 * NN;
  float* xsrc = ws + 386 * NN;
  float* NB = ws + 1026 * NN;
  float* qk = ws + 1666 * NN;
  float* sm = ws + 1676 * NN;
  float* A = ws + 1686 * NN;
  float* Cg = ws + 1686 * NN + 64 * EE;
  float* Cb = Cg + 64;

  float* node_out = (float*)d_out;
  float* edge_out = (float*)d_out + (size_t)NN * 640;

  k_init<<<1024, 256, 0, stream>>>(ws);
  k_prep<<<64, 64, 0, stream>>>(W5, g1, b1, Cg, Cb, wbuf);
  k_prepw<<<dim3(64, 15), 64, 0, stream>>>(Wnq, Wnk, Wnv, W4, W_src, wbuf);
  k_scatter<<<EE * 64 / 256, 256, 0, stream>>>(ei, edge_attr, deg, dout, sum_in, sum_src);
  k_am<<<EE / 64, 256, 0, stream>>>(edge_attr, wbuf, A);
  k_xsrcm<<<dim3(NN / 64, 10), 256, 0, stream>>>(x, wbuf, xsrc);
  k_eaqkv<<<250, 256, 0, stream>>>(deg, sum_in, sum_src, Wek, Weq, Wev, eaQ, eaK, eaV);
  k_qkm<<<NN * HH / 64, 256, 0, stream>>>(xsrc, wbuf, eaQ, eaK, dout, qk);
  k_softmax<<<(NN + 255) / 256, 256, 0, stream>>>(qk, sm);
  k_updm<<<NN * HH / 64, 256, 0, stream>>>(xsrc, wbuf, eaV, dout, sm, bias, node_out, NB);
  k_edge5<<<EE / 64, 256, 0, stream>>>(ei, edge_attr, NB, A, wbuf, Cg, Cb, g1, g2, b2,
                                       edge_out);
}

// Round 12
// 185.151 us; speedup vs baseline: 1.7115x; 1.0156x over previous
//
#include <hip/hip_runtime.h>
#include <cstdint>
#include <cstddef>

#define NN 8000
#define EE 64000
#define HH 10

// wbuf (unsigned short) offsets
#define OFF_W5T 0
#define OFF_WNQ 4096
#define OFF_WNQL 8192
#define OFF_WNK 12288
#define OFF_WNKL 16384
#define OFF_WNV 20480
#define OFF_WNVL 24576
#define OFF_W4B 28672
#define OFF_W4T 32768
#define OFF_WSRC 36864
#define OFF_WSRCL 77824

typedef __attribute__((ext_vector_type(8))) short bf16x8;
typedef __attribute__((ext_vector_type(4))) float f32x4;
typedef __attribute__((ext_vector_type(4))) unsigned int u32x4;

__device__ __forceinline__ int rfl(int v) { return __builtin_amdgcn_readfirstlane(v); }

__device__ __forceinline__ unsigned int rne16(float w) {
  unsigned int b = __float_as_uint(w);
  return (b + 0x7FFFu + ((b >> 16) & 1u)) >> 16;
}

__device__ __forceinline__ bf16x8 pack8(f32x4 a, f32x4 b) {
  u32x4 u;
  u[0] = (__float_as_uint(a[1]) & 0xFFFF0000u) | (__float_as_uint(a[0]) >> 16);
  u[1] = (__float_as_uint(a[3]) & 0xFFFF0000u) | (__float_as_uint(a[2]) >> 16);
  u[2] = (__float_as_uint(b[1]) & 0xFFFF0000u) | (__float_as_uint(b[0]) >> 16);
  u[3] = (__float_as_uint(b[3]) & 0xFFFF0000u) | (__float_as_uint(b[2]) >> 16);
  return __builtin_bit_cast(bf16x8, u);
}

__device__ __forceinline__ void split8(f32x4 a, f32x4 b, bf16x8& hi, bf16x8& lo) {
  unsigned int h[4], l[4];
#pragma unroll
  for (int j = 0; j < 2; ++j) {
    unsigned int b0 = __float_as_uint(a[2 * j]);
    unsigned int b1 = __float_as_uint(a[2 * j + 1]);
    h[j] = (b1 & 0xFFFF0000u) | (b0 >> 16);
    float r0 = a[2 * j] - __uint_as_float(b0 & 0xFFFF0000u);
    float r1 = a[2 * j + 1] - __uint_as_float(b1 & 0xFFFF0000u);
    l[j] = (__float_as_uint(r1) & 0xFFFF0000u) | (__float_as_uint(r0) >> 16);
  }
#pragma unroll
  for (int j = 0; j < 2; ++j) {
    unsigned int b0 = __float_as_uint(b[2 * j]);
    unsigned int b1 = __float_as_uint(b[2 * j + 1]);
    h[2 + j] = (b1 & 0xFFFF0000u) | (b0 >> 16);
    float r0 = b[2 * j] - __uint_as_float(b0 & 0xFFFF0000u);
    float r1 = b[2 * j + 1] - __uint_as_float(b1 & 0xFFFF0000u);
    l[2 + j] = (__float_as_uint(r1) & 0xFFFF0000u) | (__float_as_uint(r0) >> 16);
  }
  u32x4 uh = {h[0], h[1], h[2], h[3]};
  u32x4 ul = {l[0], l[1], l[2], l[3]};
  hi = __builtin_bit_cast(bf16x8, uh);
  lo = __builtin_bit_cast(bf16x8, ul);
}

__device__ __forceinline__ f32x4 relu4(f32x4 a, f32x4 b) {
  f32x4 o;
#pragma unroll
  for (int j = 0; j < 4; ++j) o[j] = fmaxf(a[j] + b[j], 0.f);
  return o;
}

// C-layout (4 tiles, lane g,r) -> B-frag f-layout (r7-verified: shuffle both
// mt candidates from source lane, select with DEST's hiHalf).
__device__ __forceinline__ void xchg(const f32x4 us[4], int l0, int l1, bool hiHalf,
                                     f32x4& q0, f32x4& q1, f32x4& q2, f32x4& q3) {
  float vv[16];
#pragma unroll
  for (int ks = 0; ks < 2; ++ks)
#pragma unroll
    for (int i = 0; i < 8; ++i) {
      const int sl = (i < 4) ? l0 : l1;
      float vlo = __shfl(us[2 * ks][i & 3], sl, 64);
      float vhi = __shfl(us[2 * ks + 1][i & 3], sl, 64);
      vv[ks * 8 + i] = hiHalf ? vhi : vlo;
    }
  q0 = {vv[0], vv[1], vv[2], vv[3]};
  q1 = {vv[4], vv[5], vv[6], vv[7]};
  q2 = {vv[8], vv[9], vv[10], vv[11]};
  q3 = {vv[12], vv[13], vv[14], vv[15]};
}

// ---------------------------------------------------------------------------
__global__ void k_init(float* __restrict__ ws) {
  int t = blockIdx.x * 256 + threadIdx.x;
  int stride = gridDim.x * 256;
  for (int i = t; i < 130 * NN; i += stride)
    ws[i] = (i >= NN && i < 2 * NN) ? 1.0f : 0.0f;
}

// ---------------------------------------------------------------------------
__global__ void k_scatter(const int* __restrict__ ei, const float* __restrict__ ea,
                          float* __restrict__ deg, float* __restrict__ dout,
                          float* __restrict__ sum_in, float* __restrict__ sum_src) {
  int t = blockIdx.x * 256 + threadIdx.x;
  if (t >= EE * 64) return;
  int e = t >> 6, f = t & 63;
  int s = ei[e];
  int d = ei[EE + e];
  float v = ea[t];
  atomicAdd(&sum_in[d * 64 + f], v);
  atomicAdd(&sum_src[s * 64 + f], v);
  if (f == 0) {
    atomicAdd(&deg[d], 1.0f);
    atomicAdd(&dout[s], 1.0f);
  }
}

// ---------------------------------------------------------------------------
// All weight prep in one kernel. y: 0=Wnq 1=Wnk 2=Wnv 3=W4bot 4=W4top
// 5..14=Wsrc head h=y-5, 15=W5 (+Cg/Cb).
__global__ void k_prepall(const float* __restrict__ Wnq, const float* __restrict__ Wnk,
                          const float* __restrict__ Wnv, const float* __restrict__ W4,
                          const float* __restrict__ Wsrc, const float* __restrict__ W5,
                          const float* __restrict__ g1, const float* __restrict__ b1,
                          float* __restrict__ Cg, float* __restrict__ Cb,
                          unsigned short* __restrict__ wbuf) {
  const int c = blockIdx.x, f = threadIdx.x, y = blockIdx.y;
  if (y == 15) {
    float w = W5[f * 64 + c];
    wbuf[OFF_W5T + c * 64 + f] = (unsigned short)rne16(w);
    float cg = g1[f] * w;
    float cb = b1[f] * w;
#pragma unroll
    for (int off = 1; off < 64; off <<= 1) {
      cg += __shfl_xor(cg, off, 64);
      cb += __shfl_xor(cb, off, 64);
    }
    if (f == 0) {
      Cg[c] = cg;
      Cb[c] = cb;
    }
    return;
  }
  float w;
  int hioff, looff = -1;
  const int cf = c * 64 + f;
  if (y == 0) { w = Wnq[f * 64 + c]; hioff = OFF_WNQ + cf; looff = OFF_WNQL + cf; }
  else if (y == 1) { w = Wnk[f * 64 + c]; hioff = OFF_WNK + cf; looff = OFF_WNKL + cf; }
  else if (y == 2) { w = Wnv[f * 64 + c]; hioff = OFF_WNV + cf; looff = OFF_WNVL + cf; }
  else if (y == 3) { w = W4[(64 + f) * 64 + c]; hioff = OFF_W4B + cf; }
  else if (y == 4) { w = W4[f * 64 + c]; hioff = OFF_W4T + cf; }
  else {
    int h = y - 5;
    w = Wsrc[f * 640 + h * 64 + c];
    hioff = OFF_WSRC + (h * 64 + c) * 64 + f;
    looff = OFF_WSRCL + (h * 64 + c) * 64 + f;
  }
  unsigned int hi = rne16(w);
  wbuf[hioff] = (unsigned short)hi;
  if (looff >= 0) {
    float rest = w - __uint_as_float(hi << 16);
    wbuf[looff] = (unsigned short)rne16(rest);
  }
}

// ---------------------------------------------------------------------------
// xsrc[(n*10+h)*64+c] = sum_f x[n][f]*Wsrc[f][h*64+c], 3-term hi/lo (fp32-level).
__global__ __launch_bounds__(256) void k_xsrcm(const float* __restrict__ x,
                                               const unsigned short* __restrict__ wbuf,
                                               float* __restrict__ xsrc) {
  const int lane = threadIdx.x & 63;
  const int wv = rfl((int)threadIdx.x >> 6);
  const int g = lane >> 4, r = lane & 15;
  const int h = blockIdx.y;
  const int n = (blockIdx.x * 4 + wv) * 16 + r;  // grid.x exact: NN/64
  bf16x8 whi[4][2], wlo[4][2];
#pragma unroll
  for (int mt = 0; mt < 4; ++mt)
#pragma unroll
    for (int ks = 0; ks < 2; ++ks) {
      const int off = (h * 64 + 16 * mt + r) * 64 + 32 * ks + 8 * g;
      whi[mt][ks] = *reinterpret_cast<const bf16x8*>(wbuf + OFF_WSRC + off);
      wlo[mt][ks] = *reinterpret_cast<const bf16x8*>(wbuf + OFF_WSRCL + off);
    }
  const float* xr = x + (size_t)n * 64 + 8 * g;
  bf16x8 xh0, xl0, xh1, xl1;
  split8(*reinterpret_cast<const f32x4*>(xr), *reinterpret_cast<const f32x4*>(xr + 4), xh0, xl0);
  split8(*reinterpret_cast<const f32x4*>(xr + 32), *reinterpret_cast<const f32x4*>(xr + 36), xh1, xl1);
  const size_t base = ((size_t)n * 10 + h) * 64;
#pragma unroll
  for (int mt = 0; mt < 4; ++mt) {
    f32x4 d = {0, 0, 0, 0};
    d = __builtin_amdgcn_mfma_f32_16x16x32_bf16(whi[mt][0], xh0, d, 0, 0, 0);
    d = __builtin_amdgcn_mfma_f32_16x16x32_bf16(whi[mt][1], xh1, d, 0, 0, 0);
    d = __builtin_amdgcn_mfma_f32_16x16x32_bf16(whi[mt][0], xl0, d, 0, 0, 0);
    d = __builtin_amdgcn_mfma_f32_16x16x32_bf16(whi[mt][1], xl1, d, 0, 0, 0);
    d = __builtin_amdgcn_mfma_f32_16x16x32_bf16(wlo[mt][0], xh0, d, 0, 0, 0);
    d = __builtin_amdgcn_mfma_f32_16x16x32_bf16(wlo[mt][1], xh1, d, 0, 0, 0);
    *reinterpret_cast<f32x4*>(xsrc + base + 16 * mt + 4 * g) = d;
  }
}

// ---------------------------------------------------------------------------
__global__ __launch_bounds__(256) void k_eaqkv(const float* __restrict__ deg,
                                               const float* __restrict__ sum_in,
                                               const float* __restrict__ sum_src,
                                               const float* __restrict__ Wek,
                                               const float* __restrict__ Weq,
                                               const float* __restrict__ Wev,
                                               float* __restrict__ eaQ,
                                               float* __restrict__ eaK,
                                               float* __restrict__ eaV) {
  const int lane = threadIdx.x & 63;
  const int wv = rfl(threadIdx.x >> 6);
  float wq[64], wk[64], wvv[64];
#pragma unroll
  for (int f = 0; f < 64; ++f) {
    wq[f] = Wek[f * 64 + lane];
    wk[f] = Weq[f * 64 + lane];
    wvv[f] = Wev[f * 64 + lane];
  }
  const int nw = gridDim.x * 4;
  for (int n = blockIdx.x * 4 + wv; n < NN; n += nw) {
    const float* si = sum_in + (size_t)n * 64;
    const float* ss = sum_src + (size_t)n * 64;
    const float invd = 1.0f / fmaxf(deg[n], 1.0f);
    float q0 = 0, q1 = 0, k0 = 0, k1 = 0, v0 = 0, v1 = 0;
#pragma unroll
    for (int f = 0; f < 64; f += 2) {
      float e0 = fmaf(si[f], invd, ss[f]);
      float e1 = fmaf(si[f + 1], invd, ss[f + 1]);
      q0 = fmaf(e0, wq[f], q0);
      q1 = fmaf(e1, wq[f + 1], q1);
      k0 = fmaf(e0, wk[f], k0);
      k1 = fmaf(e1, wk[f + 1], k1);
      v0 = fmaf(e0, wvv[f], v0);
      v1 = fmaf(e1, wvv[f + 1], v1);
    }
    eaQ[(size_t)n * 64 + lane] = q0 + q1;
    eaK[(size_t)n * 64 + lane] = k0 + k1;
    eaV[(size_t)n * 64 + lane] = v0 + v1;
  }
}

// ---------------------------------------------------------------------------
// qk via 3-term hi/lo MFMA projections + exact f32 eaQ/eaK + in-register dot.
__global__ __launch_bounds__(256) void k_qkm(const float* __restrict__ xsrc,
                                             const unsigned short* __restrict__ wbuf,
                                             const float* __restrict__ eaQ,
                                             const float* __restrict__ eaK,
                                             const float* __restrict__ dout,
                                             float* __restrict__ qk) {
  const int lane = threadIdx.x & 63;
  const int wv = rfl((int)threadIdx.x >> 6);
  const int g = lane >> 4, r = lane & 15;
  const int r0 = (blockIdx.x * 4 + wv) * 16;  // grid exact: NN*HH/64
  const int grow = r0 + r;
  const int n = grow / 10;
  const float* xp = xsrc + (size_t)grow * 64 + 8 * g;
  bf16x8 xh0, xl0, xh1, xl1;
  split8(*reinterpret_cast<const f32x4*>(xp), *reinterpret_cast<const f32x4*>(xp + 4), xh0, xl0);
  split8(*reinterpret_cast<const f32x4*>(xp + 32), *reinterpret_cast<const f32x4*>(xp + 36), xh1, xl1);
  const float dn = dout[n];
  f32x4 qf[4];
#pragma unroll
  for (int mt = 0; mt < 4; ++mt) {
    const int off = (16 * mt + r) * 64 + 8 * g;
    bf16x8 ah0 = *reinterpret_cast<const bf16x8*>(wbuf + OFF_WNQ + off);
    bf16x8 ah1 = *reinterpret_cast<const bf16x8*>(wbuf + OFF_WNQ + off + 32);
    bf16x8 al0 = *reinterpret_cast<const bf16x8*>(wbuf + OFF_WNQL + off);
    bf16x8 al1 = *reinterpret_cast<const bf16x8*>(wbuf + OFF_WNQL + off + 32);
    f32x4 d = {0, 0, 0, 0};
    d = __builtin_amdgcn_mfma_f32_16x16x32_bf16(ah0, xh0, d, 0, 0, 0);
    d = __builtin_amdgcn_mfma_f32_16x16x32_bf16(ah1, xh1, d, 0, 0, 0);
    d = __builtin_amdgcn_mfma_f32_16x16x32_bf16(ah0, xl0, d, 0, 0, 0);
    d = __builtin_amdgcn_mfma_f32_16x16x32_bf16(ah1, xl1, d, 0, 0, 0);
    d = __builtin_amdgcn_mfma_f32_16x16x32_bf16(al0, xh0, d, 0, 0, 0);
    d = __builtin_amdgcn_mfma_f32_16x16x32_bf16(al1, xh1, d, 0, 0, 0);
    qf[mt] = d;
  }
  float p = 0.f;
#pragma unroll
  for (int mt = 0; mt < 4; ++mt) {
    const int off = (16 * mt + r) * 64 + 8 * g;
    bf16x8 ah0 = *reinterpret_cast<const bf16x8*>(wbuf + OFF_WNK + off);
    bf16x8 ah1 = *reinterpret_cast<const bf16x8*>(wbuf + OFF_WNK + off + 32);
    bf16x8 al0 = *reinterpret_cast<const bf16x8*>(wbuf + OFF_WNKL + off);
    bf16x8 al1 = *reinterpret_cast<const bf16x8*>(wbuf + OFF_WNKL + off + 32);
    f32x4 d = {0, 0, 0, 0};
    d = __builtin_amdgcn_mfma_f32_16x16x32_bf16(ah0, xh0, d, 0, 0, 0);
    d = __builtin_amdgcn_mfma_f32_16x16x32_bf16(ah1, xh1, d, 0, 0, 0);
    d = __builtin_amdgcn_mfma_f32_16x16x32_bf16(ah0, xl0, d, 0, 0, 0);
    d = __builtin_amdgcn_mfma_f32_16x16x32_bf16(ah1, xl1, d, 0, 0, 0);
    d = __builtin_amdgcn_mfma_f32_16x16x32_bf16(al0, xh0, d, 0, 0, 0);
    d = __builtin_amdgcn_mfma_f32_16x16x32_bf16(al1, xh1, d, 0, 0, 0);
    f32x4 eq = *reinterpret_cast<const f32x4*>(eaQ + (size_t)n * 64 + 16 * mt + 4 * g);
    f32x4 ek = *reinterpret_cast<const f32x4*>(eaK + (size_t)n * 64 + 16 * mt + 4 * g);
#pragma unroll
    for (int q = 0; q < 4; ++q) p = fmaf(qf[mt][q] + eq[q], fmaf(dn, d[q], ek[q]), p);
  }
  p += __shfl_xor(p, 16, 64);
  p += __shfl_xor(p, 32, 64);
  if (lane < 16) qk[r0 + lane] = p * 0.125f;
}

// ---------------------------------------------------------------------------
__global__ void k_softmax(const float* __restrict__ qk, float* __restrict__ sm) {
  int n = blockIdx.x * 256 + threadIdx.x;
  if (n >= NN) return;
  float v[HH];
  float mx = -1e30f;
#pragma unroll
  for (int h = 0; h < HH; ++h) {
    v[h] = qk[n * HH + h];
    mx = fmaxf(mx, v[h]);
  }
  float s = 0;
#pragma unroll
  for (int h = 0; h < HH; ++h) {
    v[h] = expf(v[h] - mx);
    s += v[h];
  }
  float inv = 1.0f / s;
#pragma unroll
  for (int h = 0; h < HH; ++h) sm[n * HH + h] = v[h] * inv;
}

// ---------------------------------------------------------------------------
// V = dout*(xsrc@Wnv)+eaV (3-term); nu = xsrc*sm*V (f32); node_out = nu+bias;
// NB = nu @ W4bot (exchange + pure-bf16 MFMA, LN-protected downstream).
__global__ __launch_bounds__(256) void k_updm(const float* __restrict__ xsrc,
                                              const unsigned short* __restrict__ wbuf,
                                              const float* __restrict__ eaV,
                                              const float* __restrict__ dout,
                                              const float* __restrict__ sm,
                                              const float* __restrict__ bias,
                                              float* __restrict__ node_out,
                                              float* __restrict__ NB) {
  const int lane = threadIdx.x & 63;
  const int wv = rfl((int)threadIdx.x >> 6);
  const int g = lane >> 4, r = lane & 15;
  const int grow = (blockIdx.x * 4 + wv) * 16 + r;  // grid exact: NN*HH/64
  const int n = grow / 10;
  const int h = grow - 10 * n;
  const float* xp = xsrc + (size_t)grow * 64;
  bf16x8 xh0, xl0, xh1, xl1;
  split8(*reinterpret_cast<const f32x4*>(xp + 8 * g), *reinterpret_cast<const f32x4*>(xp + 8 * g + 4),
         xh0, xl0);
  split8(*reinterpret_cast<const f32x4*>(xp + 8 * g + 32),
         *reinterpret_cast<const f32x4*>(xp + 8 * g + 36), xh1, xl1);
  const float dn = dout[n];
  const float wgt = sm[grow];
  f32x4 nu[4];
#pragma unroll
  for (int mt = 0; mt < 4; ++mt) {
    const int off = (16 * mt + r) * 64 + 8 * g;
    bf16x8 ah0 = *reinterpret_cast<const bf16x8*>(wbuf + OFF_WNV + off);
    bf16x8 ah1 = *reinterpret_cast<const bf16x8*>(wbuf + OFF_WNV + off + 32);
    bf16x8 al0 = *reinterpret_cast<const bf16x8*>(wbuf + OFF_WNVL + off);
    bf16x8 al1 = *reinterpret_cast<const bf16x8*>(wbuf + OFF_WNVL + off + 32);
    f32x4 vf = {0, 0, 0, 0};
    vf = __builtin_amdgcn_mfma_f32_16x16x32_bf16(ah0, xh0, vf, 0, 0, 0);
    vf = __builtin_amdgcn_mfma_f32_16x16x32_bf16(ah1, xh1, vf, 0, 0, 0);
    vf = __builtin_amdgcn_mfma_f32_16x16x32_bf16(ah0, xl0, vf, 0, 0, 0);
    vf = __builtin_amdgcn_mfma_f32_16x16x32_bf16(ah1, xl1, vf, 0, 0, 0);
    vf = __builtin_amdgcn_mfma_f32_16x16x32_bf16(al0, xh0, vf, 0, 0, 0);
    vf = __builtin_amdgcn_mfma_f32_16x16x32_bf16(al1, xh1, vf, 0, 0, 0);
    f32x4 ev = *reinterpret_cast<const f32x4*>(eaV + (size_t)n * 64 + 16 * mt + 4 * g);
    f32x4 xs = *reinterpret_cast<const f32x4*>(xp + 16 * mt + 4 * g);
    f32x4 nn;
#pragma unroll
    for (int q = 0; q < 4; ++q) nn[q] = xs[q] * wgt * fmaf(dn, vf[q], ev[q]);
    nu[mt] = nn;
    f32x4 bs = *reinterpret_cast<const f32x4*>(bias + h * 64 + 16 * mt + 4 * g);
    *reinterpret_cast<f32x4*>(node_out + (size_t)grow * 64 + 16 * mt + 4 * g) = nn + bs;
  }
  const int l0 = (((2 * g) & 3) << 4) | r;
  const int l1 = (((2 * g + 1) & 3) << 4) | r;
  const bool hiHalf = (g >= 2);
  f32x4 q0, q1, q2, q3;
  xchg(nu, l0, l1, hiHalf, q0, q1, q2, q3);
  bf16x8 nb0 = pack8(q0, q1);
  bf16x8 nb1 = pack8(q2, q3);
#pragma unroll
  for (int mt = 0; mt < 4; ++mt) {
    const int off = (16 * mt + r) * 64 + 8 * g;
    bf16x8 ba0 = *reinterpret_cast<const bf16x8*>(wbuf + OFF_W4B + off);
    bf16x8 ba1 = *reinterpret_cast<const bf16x8*>(wbuf + OFF_W4B + off + 32);
    f32x4 nf = {0, 0, 0, 0};
    nf = __builtin_amdgcn_mfma_f32_16x16x32_bf16(ba0, nb0, nf, 0, 0, 0);
    nf = __builtin_amdgcn_mfma_f32_16x16x32_bf16(ba1, nb1, nf, 0, 0, 0);
    *reinterpret_cast<f32x4*>(NB + (size_t)grow * 64 + 16 * mt + 4 * g) = nf;
  }
}

// ---------------------------------------------------------------------------
// Edge MLP v9: A computed in-register (k_am fused), 2-head software pipeline.
__global__ __launch_bounds__(256) void k_edge6(
    const int* __restrict__ ei, const float* __restrict__ ea_g,
    const float* __restrict__ NB, const unsigned short* __restrict__ wbuf,
    const float* __restrict__ Cgp, const float* __restrict__ Cbp,
    const float* __restrict__ g1v, const float* __restrict__ g2v,
    const float* __restrict__ bias2, float* __restrict__ edge_out) {
  const int lane = threadIdx.x & 63;
  const int wv = rfl((int)threadIdx.x >> 6);
  const int g = lane >> 4;
  const int r = lane & 15;
  const int e = (blockIdx.x * 4 + wv) * 16 + r;
  const int src = ei[e];
  const int l0 = (((2 * g) & 3) << 4) | r;
  const int l1 = (((2 * g + 1) & 3) << 4) | r;
  const bool hiHalf = (g >= 2);

  bf16x8 whi[4][2];
#pragma unroll
  for (int mt = 0; mt < 4; ++mt)
#pragma unroll
    for (int ks = 0; ks < 2; ++ks)
      whi[mt][ks] = *reinterpret_cast<const bf16x8*>(wbuf + OFF_W5T + (16 * mt + r) * 64 +
                                                     32 * ks + 8 * g);

  const float* EAr = ea_g + (size_t)e * 64;
  const float* ear = EAr + 8 * g;

  // ---- fused A = ea @ W4top (C-layout) -> exchange to f-layout at0..3
  f32x4 at0, at1, at2, at3;
  {
    bf16x8 eb0 = pack8(*reinterpret_cast<const f32x4*>(ear),
                       *reinterpret_cast<const f32x4*>(ear + 4));
    bf16x8 eb1 = pack8(*reinterpret_cast<const f32x4*>(ear + 32),
                       *reinterpret_cast<const f32x4*>(ear + 36));
    f32x4 ad[4];
#pragma unroll
    for (int mt = 0; mt < 4; ++mt) {
      const int off = (16 * mt + r) * 64 + 8 * g;
      bf16x8 w0 = *reinterpret_cast<const bf16x8*>(wbuf + OFF_W4T + off);
      bf16x8 w1 = *reinterpret_cast<const bf16x8*>(wbuf + OFF_W4T + off + 32);
      f32x4 d = {0, 0, 0, 0};
      d = __builtin_amdgcn_mfma_f32_16x16x32_bf16(w0, eb0, d, 0, 0, 0);
      d = __builtin_amdgcn_mfma_f32_16x16x32_bf16(w1, eb1, d, 0, 0, 0);
      ad[mt] = d;
    }
    xchg(ad, l0, l1, hiHalf, at0, at1, at2, at3);
  }

  const float* NBr = NB + (size_t)src * 640 + 8 * g;
  f32x4 outacc[4] = {{0, 0, 0, 0}, {0, 0, 0, 0}, {0, 0, 0, 0}, {0, 0, 0, 0}};

#pragma unroll 1
  for (int hp = 0; hp < 5; ++hp) {
    const float* nbA = NBr + (2 * hp) * 64;
    const float* nbB = nbA + 64;
    // ---- B1 frags, both heads
    bf16x8 mA0 = pack8(relu4(at0, *reinterpret_cast<const f32x4*>(nbA)),
                       relu4(at1, *reinterpret_cast<const f32x4*>(nbA + 4)));
    bf16x8 mA1 = pack8(relu4(at2, *reinterpret_cast<const f32x4*>(nbA + 32)),
                       relu4(at3, *reinterpret_cast<const f32x4*>(nbA + 36)));
    bf16x8 mB0 = pack8(relu4(at0, *reinterpret_cast<const f32x4*>(nbB)),
                       relu4(at1, *reinterpret_cast<const f32x4*>(nbB + 4)));
    bf16x8 mB1 = pack8(relu4(at2, *reinterpret_cast<const f32x4*>(nbB + 32)),
                       relu4(at3, *reinterpret_cast<const f32x4*>(nbB + 36)));

    // ---- MFMA1 both heads (independent chains)
    f32x4 aA[4], aB[4];
#pragma unroll
    for (int mt = 0; mt < 4; ++mt) {
      f32x4 c = *reinterpret_cast<const f32x4*>(EAr + 16 * mt + 4 * g);
      f32x4 dA = __builtin_amdgcn_mfma_f32_16x16x32_bf16(whi[mt][0], mA0, c, 0, 0, 0);
      f32x4 dB = __builtin_amdgcn_mfma_f32_16x16x32_bf16(whi[mt][0], mB0, c, 0, 0, 0);
      dA = __builtin_amdgcn_mfma_f32_16x16x32_bf16(whi[mt][1], mA1, dA, 0, 0, 0);
      dB = __builtin_amdgcn_mfma_f32_16x16x32_bf16(whi[mt][1], mB1, dB, 0, 0, 0);
      aA[mt] = dA;
      aB[mt] = dB;
    }

    // ---- LN1 stats, 4 interleaved butterfly streams
    float sA = 0.f, s2A = 0.f, sB = 0.f, s2B = 0.f;
#pragma unroll
    for (int mt = 0; mt < 4; ++mt)
#pragma unroll
      for (int q = 0; q < 4; ++q) {
        float vA = aA[mt][q], vB = aB[mt][q];
        sA += vA; s2A = fmaf(vA, vA, s2A);
        sB += vB; s2B = fmaf(vB, vB, s2B);
      }
    sA += __shfl_xor(sA, 16, 64); sB += __shfl_xor(sB, 16, 64);
    s2A += __shfl_xor(s2A, 16, 64); s2B += __shfl_xor(s2B, 16, 64);
    sA += __shfl_xor(sA, 32, 64); sB += __shfl_xor(sB, 32, 64);
    s2A += __shfl_xor(s2A, 32, 64); s2B += __shfl_xor(s2B, 32, 64);
    const float muA = sA * 0.015625f, muB = sB * 0.015625f;
    const float rsA = rsqrtf(fmaxf(s2A * 0.015625f - muA * muA, 1e-30f));
    const float rsB = rsqrtf(fmaxf(s2B * 0.015625f - muB * muB, 1e-30f));

    // ---- scale in place, exchange both heads
#pragma unroll
    for (int mt = 0; mt < 4; ++mt) {
      f32x4 gv = *reinterpret_cast<const f32x4*>(g1v + 16 * mt + 4 * g);
      aA[mt] = aA[mt] * gv * rsA;
      aB[mt] = aB[mt] * gv * rsB;
    }
    f32x4 qA0, qA1, qA2, qA3, qB0, qB1, qB2, qB3;
    xchg(aA, l0, l1, hiHalf, qA0, qA1, qA2, qA3);
    xchg(aB, l0, l1, hiHalf, qB0, qB1, qB2, qB3);
    bf16x8 bA0 = pack8(qA0, qA1), bA1 = pack8(qA2, qA3);
    bf16x8 bB0 = pack8(qB0, qB1), bB1 = pack8(qB2, qB3);

    // ---- MFMA2 both heads
    const float mrA = muA * rsA, mrB = muB * rsB;
#pragma unroll
    for (int mt = 0; mt < 4; ++mt) {
      f32x4 eav = *reinterpret_cast<const f32x4*>(EAr + 16 * mt + 4 * g);
      f32x4 cbv = *reinterpret_cast<const f32x4*>(Cbp + 16 * mt + 4 * g);
      f32x4 cgv = *reinterpret_cast<const f32x4*>(Cgp + 16 * mt + 4 * g);
      f32x4 base = eav + cbv;
      f32x4 dA = base - mrA * cgv;
      f32x4 dB = base - mrB * cgv;
      dA = __builtin_amdgcn_mfma_f32_16x16x32_bf16(whi[mt][0], bA0, dA, 0, 0, 0);
      dB = __builtin_amdgcn_mfma_f32_16x16x32_bf16(whi[mt][0], bB0, dB, 0, 0, 0);
      dA = __builtin_amdgcn_mfma_f32_16x16x32_bf16(whi[mt][1], bA1, dA, 0, 0, 0);
      dB = __builtin_amdgcn_mfma_f32_16x16x32_bf16(whi[mt][1], bB1, dB, 0, 0, 0);
      aA[mt] = dA;  // reuse arrays for acc2
      aB[mt] = dB;
    }

    // ---- LN2 stats, both heads
    float tA = 0.f, t2A = 0.f, tB = 0.f, t2B = 0.f;
#pragma unroll
    for (int mt = 0; mt < 4; ++mt)
#pragma unroll
      for (int q = 0; q < 4; ++q) {
        float vA = aA[mt][q], vB = aB[mt][q];
        tA += vA; t2A = fmaf(vA, vA, t2A);
        tB += vB; t2B = fmaf(vB, vB, t2B);
      }
    tA += __shfl_xor(tA, 16, 64); tB += __shfl_xor(tB, 16, 64);
    t2A += __shfl_xor(t2A, 16, 64); t2B += __shfl_xor(t2B, 16, 64);
    tA += __shfl_xor(tA, 32, 64); tB += __shfl_xor(tB, 32, 64);
    t2A += __shfl_xor(t2A, 32, 64); t2B += __shfl_xor(t2B, 32, 64);
    const float m2A = tA * 0.015625f, m2B = tB * 0.015625f;
    const float r2A = rsqrtf(fmaxf(t2A * 0.015625f - m2A * m2A, 1e-30f));
    const float r2B = rsqrtf(fmaxf(t2B * 0.015625f - m2B * m2B, 1e-30f));
#pragma unroll
    for (int mt = 0; mt < 4; ++mt) {
      f32x4 g2f = *reinterpret_cast<const f32x4*>(g2v + 16 * mt + 4 * g);
      f32x4 b2f = *reinterpret_cast<const f32x4*>(bias2 + 16 * mt + 4 * g);
      outacc[mt] += (aA[mt] - m2A) * r2A * g2f + b2f;
      outacc[mt] += (aB[mt] - m2B) * r2B * g2f + b2f;
    }
  }

#pragma unroll
  for (int mt = 0; mt < 4; ++mt) {
    f32x4 o = outacc[mt] * 0.1f;
    *reinterpret_cast<f32x4*>(edge_out + (size_t)e * 64 + 16 * mt + 4 * g) = o;
  }
}

// ---------------------------------------------------------------------------
extern "C" void kernel_launch(void* const* d_in, const int* in_sizes, int n_in,
                              void* d_out, int out_size, void* d_ws, size_t ws_size,
                              hipStream_t stream) {
  const float* x = (const float*)d_in[0];
  const int* ei = (const int*)d_in[1];
  const float* edge_attr = (const float*)d_in[2];
  const float* W_src = (const float*)d_in[3];
  const float* Wnq = (const float*)d_in[4];
  const float* Wnk = (const float*)d_in[5];
  const float* Wnv = (const float*)d_in[6];
  const float* Weq = (const float*)d_in[7];
  const float* Wev = (const float*)d_in[8];
  const float* Wek = (const float*)d_in[9];
  const float* W4 = (const float*)d_in[10];
  const float* W5 = (const float*)d_in[11];
  const float* g1 = (const float*)d_in[12];
  const float* b1 = (const float*)d_in[13];
  const float* g2 = (const float*)d_in[14];
  const float* b2 = (const float*)d_in[15];
  const float* bias = (const float*)d_in[16];
  (void)in_sizes; (void)n_in; (void)out_size; (void)ws_size;

  float* ws = (float*)d_ws;
  float* deg = ws;
  float* dout = ws + NN;
  float* sum_in = ws + 2 * NN;
  float* sum_src = ws + 66 * NN;
  unsigned short* wbuf = (unsigned short*)(ws + 130 * NN);
  float* eaQ = ws + 194 * NN;
  float* eaK = ws + 258 * NN;
  float* eaV = ws + 322 * NN;
  float* xsrc = ws + 386 * NN;
  float* NB = ws + 1026 * NN;
  float* qk = ws + 1666 * NN;
  float* sm = ws + 1676 * NN;
  float* Cg = ws + 1686 * NN + 64 * EE;
  float* Cb = Cg + 64;

  float* node_out = (float*)d_out;
  float* edge_out = (float*)d_out + (size_t)NN * 640;

  k_init<<<1024, 256, 0, stream>>>(ws);
  k_prepall<<<dim3(64, 16), 64, 0, stream>>>(Wnq, Wnk, Wnv, W4, W_src, W5, g1, b1, Cg, Cb,
                                             wbuf);
  k_scatter<<<EE * 64 / 256, 256, 0, stream>>>(ei, edge_attr, deg, dout, sum_in, sum_src);
  k_xsrcm<<<dim3(NN / 64, 10), 256, 0, stream>>>(x, wbuf, xsrc);
  k_eaqkv<<<250, 256, 0, stream>>>(deg, sum_in, sum_src, Wek, Weq, Wev, eaQ, eaK, eaV);
  k_qkm<<<NN * HH / 64, 256, 0, stream>>>(xsrc, wbuf, eaQ, eaK, dout, qk);
  k_softmax<<<(NN + 255) / 256, 256, 0, stream>>>(qk, sm);
  k_updm<<<NN * HH / 64, 256, 0, stream>>>(xsrc, wbuf, eaV, dout, sm, bias, node_out, NB);
  k_edge6<<<EE / 64, 256, 0, stream>>>(ei, edge_attr, NB, wbuf, Cg, Cb, g1, g2, b2,
                                       edge_out);
}

// Round 13
// 174.217 us; speedup vs baseline: 1.8190x; 1.0628x over previous
//
#include <hip/hip_runtime.h>
#include <cstdint>
#include <cstddef>

#define NN 8000
#define EE 64000
#define HH 10

// wbuf (unsigned short) offsets
#define OFF_W5T 0      // PERMUTED: W5T[c'][k] = W5[cb(k)][c']
#define OFF_WNQ 4096
#define OFF_WNQL 8192
#define OFF_WNK 12288
#define OFF_WNKL 16384
#define OFF_WNV 20480
#define OFF_WNVL 24576
#define OFF_W4B 28672  // PERMUTED: W4B[c'][k] = W4[64+cb(k)][c']
#define OFF_W4T 32768
#define OFF_WSRC 36864
#define OFF_WSRCL 77824

typedef __attribute__((ext_vector_type(8))) short bf16x8;
typedef __attribute__((ext_vector_type(4))) float f32x4;
typedef __attribute__((ext_vector_type(4))) unsigned int u32x4;

__device__ __forceinline__ int rfl(int v) { return __builtin_amdgcn_readfirstlane(v); }

// Contraction-index permutation: position k (= 32ks+8g+i) holds true channel
// cb(k) = 32ks + 16*(i>=4) + 4g + (i&3). Bijective within each 32-slice, so
// MFMA's positional A*B pairing sums over true channels when BOTH the weight
// array and the B operand use it. C-layout regs (mt=2ks+(i>=4), q=i&3) then
// pack DIRECTLY into B-frags -- no cross-lane exchange.
__device__ __forceinline__ int cbperm(int k) {
  return 32 * (k >> 5) + 16 * ((k >> 2) & 1) + 4 * ((k >> 3) & 3) + (k & 3);
}

__device__ __forceinline__ unsigned int rne16(float w) {
  unsigned int b = __float_as_uint(w);
  return (b + 0x7FFFu + ((b >> 16) & 1u)) >> 16;
}

__device__ __forceinline__ bf16x8 pack8(f32x4 a, f32x4 b) {
  u32x4 u;
  u[0] = (__float_as_uint(a[1]) & 0xFFFF0000u) | (__float_as_uint(a[0]) >> 16);
  u[1] = (__float_as_uint(a[3]) & 0xFFFF0000u) | (__float_as_uint(a[2]) >> 16);
  u[2] = (__float_as_uint(b[1]) & 0xFFFF0000u) | (__float_as_uint(b[0]) >> 16);
  u[3] = (__float_as_uint(b[3]) & 0xFFFF0000u) | (__float_as_uint(b[2]) >> 16);
  return __builtin_bit_cast(bf16x8, u);
}

__device__ __forceinline__ void split8(f32x4 a, f32x4 b, bf16x8& hi, bf16x8& lo) {
  unsigned int h[4], l[4];
#pragma unroll
  for (int j = 0; j < 2; ++j) {
    unsigned int b0 = __float_as_uint(a[2 * j]);
    unsigned int b1 = __float_as_uint(a[2 * j + 1]);
    h[j] = (b1 & 0xFFFF0000u) | (b0 >> 16);
    float r0 = a[2 * j] - __uint_as_float(b0 & 0xFFFF0000u);
    float r1 = a[2 * j + 1] - __uint_as_float(b1 & 0xFFFF0000u);
    l[j] = (__float_as_uint(r1) & 0xFFFF0000u) | (__float_as_uint(r0) >> 16);
  }
#pragma unroll
  for (int j = 0; j < 2; ++j) {
    unsigned int b0 = __float_as_uint(b[2 * j]);
    unsigned int b1 = __float_as_uint(b[2 * j + 1]);
    h[2 + j] = (b1 & 0xFFFF0000u) | (b0 >> 16);
    float r0 = b[2 * j] - __uint_as_float(b0 & 0xFFFF0000u);
    float r1 = b[2 * j + 1] - __uint_as_float(b1 & 0xFFFF0000u);
    l[2 + j] = (__float_as_uint(r1) & 0xFFFF0000u) | (__float_as_uint(r0) >> 16);
  }
  u32x4 uh = {h[0], h[1], h[2], h[3]};
  u32x4 ul = {l[0], l[1], l[2], l[3]};
  hi = __builtin_bit_cast(bf16x8, uh);
  lo = __builtin_bit_cast(bf16x8, ul);
}

__device__ __forceinline__ f32x4 relu4(f32x4 a, f32x4 b) {
  f32x4 o;
#pragma unroll
  for (int j = 0; j < 4; ++j) o[j] = fmaxf(a[j] + b[j], 0.f);
  return o;
}

// ---------------------------------------------------------------------------
__global__ void k_init(float* __restrict__ ws) {
  int t = blockIdx.x * 256 + threadIdx.x;
  int stride = gridDim.x * 256;
  for (int i = t; i < 130 * NN; i += stride)
    ws[i] = (i >= NN && i < 2 * NN) ? 1.0f : 0.0f;
}

// ---------------------------------------------------------------------------
__global__ void k_scatter(const int* __restrict__ ei, const float* __restrict__ ea,
                          float* __restrict__ deg, float* __restrict__ dout,
                          float* __restrict__ sum_in, float* __restrict__ sum_src) {
  int t = blockIdx.x * 256 + threadIdx.x;
  if (t >= EE * 64) return;
  int e = t >> 6, f = t & 63;
  int s = ei[e];
  int d = ei[EE + e];
  float v = ea[t];
  atomicAdd(&sum_in[d * 64 + f], v);
  atomicAdd(&sum_src[s * 64 + f], v);
  if (f == 0) {
    atomicAdd(&deg[d], 1.0f);
    atomicAdd(&dout[s], 1.0f);
  }
}

// ---------------------------------------------------------------------------
// y: 0=Wnq 1=Wnk 2=Wnv 3=W4bot(PERMUTED) 4=W4top 5..14=Wsrc h=y-5,
// 15=W5(PERMUTED)+Cg/Cb. Cg/Cb sums are over the cb bijection == true sums.
__global__ void k_prepall(const float* __restrict__ Wnq, const float* __restrict__ Wnk,
                          const float* __restrict__ Wnv, const float* __restrict__ W4,
                          const float* __restrict__ Wsrc, const float* __restrict__ W5,
                          const float* __restrict__ g1, const float* __restrict__ b1,
                          float* __restrict__ Cg, float* __restrict__ Cb,
                          unsigned short* __restrict__ wbuf) {
  const int c = blockIdx.x, f = threadIdx.x, y = blockIdx.y;
  if (y == 15) {
    const int cb = cbperm(f);
    float w = W5[cb * 64 + c];
    wbuf[OFF_W5T + c * 64 + f] = (unsigned short)rne16(w);
    float cg = g1[cb] * w;
    float cbb = b1[cb] * w;
#pragma unroll
    for (int off = 1; off < 64; off <<= 1) {
      cg += __shfl_xor(cg, off, 64);
      cbb += __shfl_xor(cbb, off, 64);
    }
    if (f == 0) {
      Cg[c] = cg;
      Cb[c] = cbb;
    }
    return;
  }
  float w;
  int hioff, looff = -1;
  const int cf = c * 64 + f;
  if (y == 0) { w = Wnq[f * 64 + c]; hioff = OFF_WNQ + cf; looff = OFF_WNQL + cf; }
  else if (y == 1) { w = Wnk[f * 64 + c]; hioff = OFF_WNK + cf; looff = OFF_WNKL + cf; }
  else if (y == 2) { w = Wnv[f * 64 + c]; hioff = OFF_WNV + cf; looff = OFF_WNVL + cf; }
  else if (y == 3) { w = W4[(64 + cbperm(f)) * 64 + c]; hioff = OFF_W4B + cf; }
  else if (y == 4) { w = W4[f * 64 + c]; hioff = OFF_W4T + cf; }
  else {
    int h = y - 5;
    w = Wsrc[f * 640 + h * 64 + c];
    hioff = OFF_WSRC + (h * 64 + c) * 64 + f;
    looff = OFF_WSRCL + (h * 64 + c) * 64 + f;
  }
  unsigned int hi = rne16(w);
  wbuf[hioff] = (unsigned short)hi;
  if (looff >= 0) {
    float rest = w - __uint_as_float(hi << 16);
    wbuf[looff] = (unsigned short)rne16(rest);
  }
}

// ---------------------------------------------------------------------------
// xsrc[(n*10+h)*64+c] = sum_f x[n][f]*Wsrc[f][h*64+c], 3-term hi/lo (fp32-level).
__global__ __launch_bounds__(256) void k_xsrcm(const float* __restrict__ x,
                                               const unsigned short* __restrict__ wbuf,
                                               float* __restrict__ xsrc) {
  const int lane = threadIdx.x & 63;
  const int wv = rfl((int)threadIdx.x >> 6);
  const int g = lane >> 4, r = lane & 15;
  const int h = blockIdx.y;
  const int n = (blockIdx.x * 4 + wv) * 16 + r;  // grid.x exact: NN/64
  bf16x8 whi[4][2], wlo[4][2];
#pragma unroll
  for (int mt = 0; mt < 4; ++mt)
#pragma unroll
    for (int ks = 0; ks < 2; ++ks) {
      const int off = (h * 64 + 16 * mt + r) * 64 + 32 * ks + 8 * g;
      whi[mt][ks] = *reinterpret_cast<const bf16x8*>(wbuf + OFF_WSRC + off);
      wlo[mt][ks] = *reinterpret_cast<const bf16x8*>(wbuf + OFF_WSRCL + off);
    }
  const float* xr = x + (size_t)n * 64 + 8 * g;
  bf16x8 xh0, xl0, xh1, xl1;
  split8(*reinterpret_cast<const f32x4*>(xr), *reinterpret_cast<const f32x4*>(xr + 4), xh0, xl0);
  split8(*reinterpret_cast<const f32x4*>(xr + 32), *reinterpret_cast<const f32x4*>(xr + 36), xh1, xl1);
  const size_t base = ((size_t)n * 10 + h) * 64;
#pragma unroll
  for (int mt = 0; mt < 4; ++mt) {
    f32x4 d = {0, 0, 0, 0};
    d = __builtin_amdgcn_mfma_f32_16x16x32_bf16(whi[mt][0], xh0, d, 0, 0, 0);
    d = __builtin_amdgcn_mfma_f32_16x16x32_bf16(whi[mt][1], xh1, d, 0, 0, 0);
    d = __builtin_amdgcn_mfma_f32_16x16x32_bf16(whi[mt][0], xl0, d, 0, 0, 0);
    d = __builtin_amdgcn_mfma_f32_16x16x32_bf16(whi[mt][1], xl1, d, 0, 0, 0);
    d = __builtin_amdgcn_mfma_f32_16x16x32_bf16(wlo[mt][0], xh0, d, 0, 0, 0);
    d = __builtin_amdgcn_mfma_f32_16x16x32_bf16(wlo[mt][1], xh1, d, 0, 0, 0);
    *reinterpret_cast<f32x4*>(xsrc + base + 16 * mt + 4 * g) = d;
  }
}

// ---------------------------------------------------------------------------
__global__ __launch_bounds__(256) void k_eaqkv(const float* __restrict__ deg,
                                               const float* __restrict__ sum_in,
                                               const float* __restrict__ sum_src,
                                               const float* __restrict__ Wek,
                                               const float* __restrict__ Weq,
                                               const float* __restrict__ Wev,
                                               float* __restrict__ eaQ,
                                               float* __restrict__ eaK,
                                               float* __restrict__ eaV) {
  const int lane = threadIdx.x & 63;
  const int wv = rfl(threadIdx.x >> 6);
  float wq[64], wk[64], wvv[64];
#pragma unroll
  for (int f = 0; f < 64; ++f) {
    wq[f] = Wek[f * 64 + lane];
    wk[f] = Weq[f * 64 + lane];
    wvv[f] = Wev[f * 64 + lane];
  }
  const int nw = gridDim.x * 4;
  for (int n = blockIdx.x * 4 + wv; n < NN; n += nw) {
    const float* si = sum_in + (size_t)n * 64;
    const float* ss = sum_src + (size_t)n * 64;
    const float invd = 1.0f / fmaxf(deg[n], 1.0f);
    float q0 = 0, q1 = 0, k0 = 0, k1 = 0, v0 = 0, v1 = 0;
#pragma unroll
    for (int f = 0; f < 64; f += 2) {
      float e0 = fmaf(si[f], invd, ss[f]);
      float e1 = fmaf(si[f + 1], invd, ss[f + 1]);
      q0 = fmaf(e0, wq[f], q0);
      q1 = fmaf(e1, wq[f + 1], q1);
      k0 = fmaf(e0, wk[f], k0);
      k1 = fmaf(e1, wk[f + 1], k1);
      v0 = fmaf(e0, wvv[f], v0);
      v1 = fmaf(e1, wvv[f + 1], v1);
    }
    eaQ[(size_t)n * 64 + lane] = q0 + q1;
    eaK[(size_t)n * 64 + lane] = k0 + k1;
    eaV[(size_t)n * 64 + lane] = v0 + v1;
  }
}

// ---------------------------------------------------------------------------
// qk via 3-term hi/lo MFMA projections + exact f32 eaQ/eaK + in-register dot.
__global__ __launch_bounds__(256) void k_qkm(const float* __restrict__ xsrc,
                                             const unsigned short* __restrict__ wbuf,
                                             const float* __restrict__ eaQ,
                                             const float* __restrict__ eaK,
                                             const float* __restrict__ dout,
                                             float* __restrict__ qk) {
  const int lane = threadIdx.x & 63;
  const int wv = rfl((int)threadIdx.x >> 6);
  const int g = lane >> 4, r = lane & 15;
  const int r0 = (blockIdx.x * 4 + wv) * 16;  // grid exact: NN*HH/64
  const int grow = r0 + r;
  const int n = grow / 10;
  const float* xp = xsrc + (size_t)grow * 64 + 8 * g;
  bf16x8 xh0, xl0, xh1, xl1;
  split8(*reinterpret_cast<const f32x4*>(xp), *reinterpret_cast<const f32x4*>(xp + 4), xh0, xl0);
  split8(*reinterpret_cast<const f32x4*>(xp + 32), *reinterpret_cast<const f32x4*>(xp + 36), xh1, xl1);
  const float dn = dout[n];
  f32x4 qf[4];
#pragma unroll
  for (int mt = 0; mt < 4; ++mt) {
    const int off = (16 * mt + r) * 64 + 8 * g;
    bf16x8 ah0 = *reinterpret_cast<const bf16x8*>(wbuf + OFF_WNQ + off);
    bf16x8 ah1 = *reinterpret_cast<const bf16x8*>(wbuf + OFF_WNQ + off + 32);
    bf16x8 al0 = *reinterpret_cast<const bf16x8*>(wbuf + OFF_WNQL + off);
    bf16x8 al1 = *reinterpret_cast<const bf16x8*>(wbuf + OFF_WNQL + off + 32);
    f32x4 d = {0, 0, 0, 0};
    d = __builtin_amdgcn_mfma_f32_16x16x32_bf16(ah0, xh0, d, 0, 0, 0);
    d = __builtin_amdgcn_mfma_f32_16x16x32_bf16(ah1, xh1, d, 0, 0, 0);
    d = __builtin_amdgcn_mfma_f32_16x16x32_bf16(ah0, xl0, d, 0, 0, 0);
    d = __builtin_amdgcn_mfma_f32_16x16x32_bf16(ah1, xl1, d, 0, 0, 0);
    d = __builtin_amdgcn_mfma_f32_16x16x32_bf16(al0, xh0, d, 0, 0, 0);
    d = __builtin_amdgcn_mfma_f32_16x16x32_bf16(al1, xh1, d, 0, 0, 0);
    qf[mt] = d;
  }
  float p = 0.f;
#pragma unroll
  for (int mt = 0; mt < 4; ++mt) {
    const int off = (16 * mt + r) * 64 + 8 * g;
    bf16x8 ah0 = *reinterpret_cast<const bf16x8*>(wbuf + OFF_WNK + off);
    bf16x8 ah1 = *reinterpret_cast<const bf16x8*>(wbuf + OFF_WNK + off + 32);
    bf16x8 al0 = *reinterpret_cast<const bf16x8*>(wbuf + OFF_WNKL + off);
    bf16x8 al1 = *reinterpret_cast<const bf16x8*>(wbuf + OFF_WNKL + off + 32);
    f32x4 d = {0, 0, 0, 0};
    d = __builtin_amdgcn_mfma_f32_16x16x32_bf16(ah0, xh0, d, 0, 0, 0);
    d = __builtin_amdgcn_mfma_f32_16x16x32_bf16(ah1, xh1, d, 0, 0, 0);
    d = __builtin_amdgcn_mfma_f32_16x16x32_bf16(ah0, xl0, d, 0, 0, 0);
    d = __builtin_amdgcn_mfma_f32_16x16x32_bf16(ah1, xl1, d, 0, 0, 0);
    d = __builtin_amdgcn_mfma_f32_16x16x32_bf16(al0, xh0, d, 0, 0, 0);
    d = __builtin_amdgcn_mfma_f32_16x16x32_bf16(al1, xh1, d, 0, 0, 0);
    f32x4 eq = *reinterpret_cast<const f32x4*>(eaQ + (size_t)n * 64 + 16 * mt + 4 * g);
    f32x4 ek = *reinterpret_cast<const f32x4*>(eaK + (size_t)n * 64 + 16 * mt + 4 * g);
#pragma unroll
    for (int q = 0; q < 4; ++q) p = fmaf(qf[mt][q] + eq[q], fmaf(dn, d[q], ek[q]), p);
  }
  p += __shfl_xor(p, 16, 64);
  p += __shfl_xor(p, 32, 64);
  if (lane < 16) qk[r0 + lane] = p * 0.125f;
}

// ---------------------------------------------------------------------------
__global__ void k_softmax(const float* __restrict__ qk, float* __restrict__ sm) {
  int n = blockIdx.x * 256 + threadIdx.x;
  if (n >= NN) return;
  float v[HH];
  float mx = -1e30f;
#pragma unroll
  for (int h = 0; h < HH; ++h) {
    v[h] = qk[n * HH + h];
    mx = fmaxf(mx, v[h]);
  }
  float s = 0;
#pragma unroll
  for (int h = 0; h < HH; ++h) {
    v[h] = expf(v[h] - mx);
    s += v[h];
  }
  float inv = 1.0f / s;
#pragma unroll
  for (int h = 0; h < HH; ++h) sm[n * HH + h] = v[h] * inv;
}

// ---------------------------------------------------------------------------
// V = dout*(xsrc@Wnv)+eaV (3-term); nu = xsrc*sm*V (f32); node_out = nu+bias;
// NB = nu @ W4bot -- nu packed DIRECTLY from C-layout, W4B is cb-permuted.
__global__ __launch_bounds__(256) void k_updm(const float* __restrict__ xsrc,
                                              const unsigned short* __restrict__ wbuf,
                                              const float* __restrict__ eaV,
                                              const float* __restrict__ dout,
                                              const float* __restrict__ sm,
                                              const float* __restrict__ bias,
                                              float* __restrict__ node_out,
                                              float* __restrict__ NB) {
  const int lane = threadIdx.x & 63;
  const int wv = rfl((int)threadIdx.x >> 6);
  const int g = lane >> 4, r = lane & 15;
  const int grow = (blockIdx.x * 4 + wv) * 16 + r;  // grid exact: NN*HH/64
  const int n = grow / 10;
  const int h = grow - 10 * n;
  const float* xp = xsrc + (size_t)grow * 64;
  bf16x8 xh0, xl0, xh1, xl1;
  split8(*reinterpret_cast<const f32x4*>(xp + 8 * g), *reinterpret_cast<const f32x4*>(xp + 8 * g + 4),
         xh0, xl0);
  split8(*reinterpret_cast<const f32x4*>(xp + 8 * g + 32),
         *reinterpret_cast<const f32x4*>(xp + 8 * g + 36), xh1, xl1);
  const float dn = dout[n];
  const float wgt = sm[grow];
  f32x4 nu[4];
#pragma unroll
  for (int mt = 0; mt < 4; ++mt) {
    const int off = (16 * mt + r) * 64 + 8 * g;
    bf16x8 ah0 = *reinterpret_cast<const bf16x8*>(wbuf + OFF_WNV + off);
    bf16x8 ah1 = *reinterpret_cast<const bf16x8*>(wbuf + OFF_WNV + off + 32);
    bf16x8 al0 = *reinterpret_cast<const bf16x8*>(wbuf + OFF_WNVL + off);
    bf16x8 al1 = *reinterpret_cast<const bf16x8*>(wbuf + OFF_WNVL + off + 32);
    f32x4 vf = {0, 0, 0, 0};
    vf = __builtin_amdgcn_mfma_f32_16x16x32_bf16(ah0, xh0, vf, 0, 0, 0);
    vf = __builtin_amdgcn_mfma_f32_16x16x32_bf16(ah1, xh1, vf, 0, 0, 0);
    vf = __builtin_amdgcn_mfma_f32_16x16x32_bf16(ah0, xl0, vf, 0, 0, 0);
    vf = __builtin_amdgcn_mfma_f32_16x16x32_bf16(ah1, xl1, vf, 0, 0, 0);
    vf = __builtin_amdgcn_mfma_f32_16x16x32_bf16(al0, xh0, vf, 0, 0, 0);
    vf = __builtin_amdgcn_mfma_f32_16x16x32_bf16(al1, xh1, vf, 0, 0, 0);
    f32x4 ev = *reinterpret_cast<const f32x4*>(eaV + (size_t)n * 64 + 16 * mt + 4 * g);
    f32x4 xs = *reinterpret_cast<const f32x4*>(xp + 16 * mt + 4 * g);
    f32x4 nn;
#pragma unroll
    for (int q = 0; q < 4; ++q) nn[q] = xs[q] * wgt * fmaf(dn, vf[q], ev[q]);
    nu[mt] = nn;
    f32x4 bs = *reinterpret_cast<const f32x4*>(bias + h * 64 + 16 * mt + 4 * g);
    *reinterpret_cast<f32x4*>(node_out + (size_t)grow * 64 + 16 * mt + 4 * g) = nn + bs;
  }
  // direct pack (cb-permutation replaces the exchange)
  bf16x8 nb0 = pack8(nu[0], nu[1]);
  bf16x8 nb1 = pack8(nu[2], nu[3]);
#pragma unroll
  for (int mt = 0; mt < 4; ++mt) {
    const int off = (16 * mt + r) * 64 + 8 * g;
    bf16x8 ba0 = *reinterpret_cast<const bf16x8*>(wbuf + OFF_W4B + off);
    bf16x8 ba1 = *reinterpret_cast<const bf16x8*>(wbuf + OFF_W4B + off + 32);
    f32x4 nf = {0, 0, 0, 0};
    nf = __builtin_amdgcn_mfma_f32_16x16x32_bf16(ba0, nb0, nf, 0, 0, 0);
    nf = __builtin_amdgcn_mfma_f32_16x16x32_bf16(ba1, nb1, nf, 0, 0, 0);
    *reinterpret_cast<f32x4*>(NB + (size_t)grow * 64 + 16 * mt + 4 * g) = nf;
  }
}

// ---------------------------------------------------------------------------
// Edge MLP v10: single-head loop (r12 lesson), fused A (C-layout, no xchg),
// cb-permuted W5T -> ZERO exchanges; per-head DS = 8 LN butterflies only.
__global__ __launch_bounds__(256) void k_edge7(
    const int* __restrict__ ei, const float* __restrict__ ea_g,
    const float* __restrict__ NB, const unsigned short* __restrict__ wbuf,
    const float* __restrict__ Cgp, const float* __restrict__ Cbp,
    const float* __restrict__ g1v, const float* __restrict__ g2v,
    const float* __restrict__ bias2, float* __restrict__ edge_out) {
  const int lane = threadIdx.x & 63;
  const int wv = rfl((int)threadIdx.x >> 6);
  const int g = lane >> 4;
  const int r = lane & 15;
  const int e = (blockIdx.x * 4 + wv) * 16 + r;
  const int src = ei[e];

  bf16x8 whi[4][2];  // cb-permuted W5T
#pragma unroll
  for (int mt = 0; mt < 4; ++mt)
#pragma unroll
    for (int ks = 0; ks < 2; ++ks)
      whi[mt][ks] = *reinterpret_cast<const bf16x8*>(wbuf + OFF_W5T + (16 * mt + r) * 64 +
                                                     32 * ks + 8 * g);

  const float* EAr = ea_g + (size_t)e * 64;
  const float* ear = EAr + 8 * g;

  // ---- fused A = ea @ W4top, KEPT in C-layout (feeds B1 via cb positions)
  f32x4 ad[4];
  {
    bf16x8 eb0 = pack8(*reinterpret_cast<const f32x4*>(ear),
                       *reinterpret_cast<const f32x4*>(ear + 4));
    bf16x8 eb1 = pack8(*reinterpret_cast<const f32x4*>(ear + 32),
                       *reinterpret_cast<const f32x4*>(ear + 36));
#pragma unroll
    for (int mt = 0; mt < 4; ++mt) {
      const int off = (16 * mt + r) * 64 + 8 * g;
      bf16x8 w0 = *reinterpret_cast<const bf16x8*>(wbuf + OFF_W4T + off);
      bf16x8 w1 = *reinterpret_cast<const bf16x8*>(wbuf + OFF_W4T + off + 32);
      f32x4 d = {0, 0, 0, 0};
      d = __builtin_amdgcn_mfma_f32_16x16x32_bf16(w0, eb0, d, 0, 0, 0);
      d = __builtin_amdgcn_mfma_f32_16x16x32_bf16(w1, eb1, d, 0, 0, 0);
      ad[mt] = d;
    }
  }

  const float* NBr = NB + (size_t)src * 640;
  f32x4 outacc[4] = {{0, 0, 0, 0}, {0, 0, 0, 0}, {0, 0, 0, 0}, {0, 0, 0, 0}};

#pragma unroll 1
  for (int h = 0; h < HH; ++h) {
    const float* nb = NBr + h * 64;
    // B1 position (ks,i): true channel cb = 32ks+16(i>=4)+4g+(i&3)
    f32x4 n0 = *reinterpret_cast<const f32x4*>(nb + 4 * g);
    f32x4 n1 = *reinterpret_cast<const f32x4*>(nb + 16 + 4 * g);
    f32x4 n2 = *reinterpret_cast<const f32x4*>(nb + 32 + 4 * g);
    f32x4 n3 = *reinterpret_cast<const f32x4*>(nb + 48 + 4 * g);
    bf16x8 bhi0 = pack8(relu4(ad[0], n0), relu4(ad[1], n1));
    bf16x8 bhi1 = pack8(relu4(ad[2], n2), relu4(ad[3], n3));

    f32x4 acc1[4];
#pragma unroll
    for (int mt = 0; mt < 4; ++mt) {
      f32x4 a = *reinterpret_cast<const f32x4*>(EAr + 16 * mt + 4 * g);
      a = __builtin_amdgcn_mfma_f32_16x16x32_bf16(whi[mt][0], bhi0, a, 0, 0, 0);
      a = __builtin_amdgcn_mfma_f32_16x16x32_bf16(whi[mt][1], bhi1, a, 0, 0, 0);
      acc1[mt] = a;
    }

    // LN1 stats for row r (lanes r, r+16, r+32, r+48)
    float s = 0.f, s2 = 0.f;
#pragma unroll
    for (int mt = 0; mt < 4; ++mt)
#pragma unroll
      for (int q = 0; q < 4; ++q) {
        float v = acc1[mt][q];
        s += v;
        s2 = fmaf(v, v, s2);
      }
    s += __shfl_xor(s, 16, 64);
    s2 += __shfl_xor(s2, 16, 64);
    s += __shfl_xor(s, 32, 64);
    s2 += __shfl_xor(s2, 32, 64);
    const float mu1 = s * 0.015625f;
    const float rs1 = rsqrtf(fmaxf(s2 * 0.015625f - mu1 * mu1, 1e-30f));

    // scale (true-index g1) and pack DIRECTLY (cb-permutation, no exchange)
#pragma unroll
    for (int mt = 0; mt < 4; ++mt) {
      f32x4 gv = *reinterpret_cast<const f32x4*>(g1v + 16 * mt + 4 * g);
      acc1[mt] = acc1[mt] * gv * rs1;
    }
    bf16x8 b20 = pack8(acc1[0], acc1[1]);
    bf16x8 b21 = pack8(acc1[2], acc1[3]);

    const float m1r1 = mu1 * rs1;
    f32x4 acc2[4];
#pragma unroll
    for (int mt = 0; mt < 4; ++mt) {
      f32x4 eav = *reinterpret_cast<const f32x4*>(EAr + 16 * mt + 4 * g);
      f32x4 cbv = *reinterpret_cast<const f32x4*>(Cbp + 16 * mt + 4 * g);
      f32x4 cgv = *reinterpret_cast<const f32x4*>(Cgp + 16 * mt + 4 * g);
      f32x4 a = eav + cbv - m1r1 * cgv;
      a = __builtin_amdgcn_mfma_f32_16x16x32_bf16(whi[mt][0], b20, a, 0, 0, 0);
      a = __builtin_amdgcn_mfma_f32_16x16x32_bf16(whi[mt][1], b21, a, 0, 0, 0);
      acc2[mt] = a;
    }

    float t = 0.f, t2 = 0.f;
#pragma unroll
    for (int mt = 0; mt < 4; ++mt)
#pragma unroll
      for (int q = 0; q < 4; ++q) {
        float v = acc2[mt][q];
        t += v;
        t2 = fmaf(v, v, t2);
      }
    t += __shfl_xor(t, 16, 64);
    t2 += __shfl_xor(t2, 16, 64);
    t += __shfl_xor(t, 32, 64);
    t2 += __shfl_xor(t2, 32, 64);
    const float mu2 = t * 0.015625f;
    const float rs2 = rsqrtf(fmaxf(t2 * 0.015625f - mu2 * mu2, 1e-30f));
#pragma unroll
    for (int mt = 0; mt < 4; ++mt) {
      f32x4 g2f = *reinterpret_cast<const f32x4*>(g2v + 16 * mt + 4 * g);
      f32x4 b2f = *reinterpret_cast<const f32x4*>(bias2 + 16 * mt + 4 * g);
      outacc[mt] += (acc2[mt] - mu2) * rs2 * g2f + b2f;
    }
  }

#pragma unroll
  for (int mt = 0; mt < 4; ++mt) {
    f32x4 o = outacc[mt] * 0.1f;
    *reinterpret_cast<f32x4*>(edge_out + (size_t)e * 64 + 16 * mt + 4 * g) = o;
  }
}

// ---------------------------------------------------------------------------
extern "C" void kernel_launch(void* const* d_in, const int* in_sizes, int n_in,
                              void* d_out, int out_size, void* d_ws, size_t ws_size,
                              hipStream_t stream) {
  const float* x = (const float*)d_in[0];
  const int* ei = (const int*)d_in[1];
  const float* edge_attr = (const float*)d_in[2];
  const float* W_src = (const float*)d_in[3];
  const float* Wnq = (const float*)d_in[4];
  const float* Wnk = (const float*)d_in[5];
  const float* Wnv = (const float*)d_in[6];
  const float* Weq = (const float*)d_in[7];
  const float* Wev = (const float*)d_in[8];
  const float* Wek = (const float*)d_in[9];
  const float* W4 = (const float*)d_in[10];
  const float* W5 = (const float*)d_in[11];
  const float* g1 = (const float*)d_in[12];
  const float* b1 = (const float*)d_in[13];
  const float* g2 = (const float*)d_in[14];
  const float* b2 = (const float*)d_in[15];
  const float* bias = (const float*)d_in[16];
  (void)in_sizes; (void)n_in; (void)out_size; (void)ws_size;

  float* ws = (float*)d_ws;
  float* deg = ws;
  float* dout = ws + NN;
  float* sum_in = ws + 2 * NN;
  float* sum_src = ws + 66 * NN;
  unsigned short* wbuf = (unsigned short*)(ws + 130 * NN);
  float* eaQ = ws + 194 * NN;
  float* eaK = ws + 258 * NN;
  float* eaV = ws + 322 * NN;
  float* xsrc = ws + 386 * NN;
  float* NB = ws + 1026 * NN;
  float* qk = ws + 1666 * NN;
  float* sm = ws + 1676 * NN;
  float* Cg = ws + 1686 * NN + 64 * EE;
  float* Cb = Cg + 64;

  float* node_out = (float*)d_out;
  float* edge_out = (float*)d_out + (size_t)NN * 640;

  k_init<<<1024, 256, 0, stream>>>(ws);
  k_prepall<<<dim3(64, 16), 64, 0, stream>>>(Wnq, Wnk, Wnv, W4, W_src, W5, g1, b1, Cg, Cb,
                                             wbuf);
  k_scatter<<<EE * 64 / 256, 256, 0, stream>>>(ei, edge_attr, deg, dout, sum_in, sum_src);
  k_xsrcm<<<dim3(NN / 64, 10), 256, 0, stream>>>(x, wbuf, xsrc);
  k_eaqkv<<<250, 256, 0, stream>>>(deg, sum_in, sum_src, Wek, Weq, Wev, eaQ, eaK, eaV);
  k_qkm<<<NN * HH / 64, 256, 0, stream>>>(xsrc, wbuf, eaQ, eaK, dout, qk);
  k_softmax<<<(NN + 255) / 256, 256, 0, stream>>>(qk, sm);
  k_updm<<<NN * HH / 64, 256, 0, stream>>>(xsrc, wbuf, eaV, dout, sm, bias, node_out, NB);
  k_edge7<<<EE / 64, 256, 0, stream>>>(ei, edge_attr, NB, wbuf, Cg, Cb, g1, g2, b2,
                                       edge_out);
}